// Round 1
// baseline (1558.661 us; speedup 1.0000x reference)
//
#include <hip/hip_runtime.h>
#include <cmath>

#define N_NODES 8192
#define N_EDGES 131072
#define NB      256
#define NH      128
#define D3      384
#define D6      768

__device__ __forceinline__ float sigf(float x){ return 1.0f/(1.0f+__expf(-x)); }

// ---------- setup: degrees, counts, scans, edge coefficients ----------

__global__ void k_init(float* deg1, float* deg2, int* cnt1, int* cnt2){
  int t = blockIdx.x*blockDim.x + threadIdx.x;
  if (t < N_NODES){ deg1[t]=1.f; deg2[t]=1.f; }   // self-loop weight 1
  if (t < NB){ cnt1[t]=0; cnt2[t]=0; }
}

__global__ void k_deg(const int* __restrict__ ei, const float* __restrict__ ew, float* deg){
  int e = blockIdx.x*blockDim.x + threadIdx.x;
  if (e < N_EDGES) atomicAdd(&deg[ei[N_EDGES+e]], ew[e]);  // dst row of edge_index
}

__global__ void k_count(const int* __restrict__ b1, const int* __restrict__ b2, int* c1, int* c2){
  int t = blockIdx.x*blockDim.x + threadIdx.x;
  if (t < N_NODES){ atomicAdd(&c1[b1[t]],1); atomicAdd(&c2[b2[t]],1); }
}

__global__ void k_dinv(float* deg1, float* deg2){
  int t = blockIdx.x*blockDim.x + threadIdx.x;
  if (t < N_NODES){ deg1[t]=rsqrtf(deg1[t]); deg2[t]=rsqrtf(deg2[t]); }  // deg>=1 always
}

__global__ void k_scan(const int* c1, const int* c2, int* st1, int* st2){
  if (threadIdx.x==0){ int s=0; for(int g=0;g<NB;g++){ st1[g]=s; s+=c1[g]; } st1[NB]=s; }
  if (threadIdx.x==1){ int s=0; for(int g=0;g<NB;g++){ st2[g]=s; s+=c2[g]; } st2[NB]=s; }
}

__global__ void k_coef(const int* __restrict__ ei, const float* __restrict__ ew,
                       const float* __restrict__ dinv, float* __restrict__ coef){
  int e = blockIdx.x*blockDim.x + threadIdx.x;
  if (e < N_EDGES) coef[e] = dinv[ei[e]]*ew[e]*dinv[ei[N_EDGES+e]];
}

// ---------- GCN layer pieces ----------

// xw[i,c] = sum_k x[i,k] * W[k,c]   (8 rows per block, 128 threads = 1 col each)
__global__ __launch_bounds__(128) void k_xw(const float* __restrict__ x, int xs, int K,
                                            const float* __restrict__ W, float* __restrict__ xw){
  __shared__ float xr[8][128];
  int i0 = blockIdx.x*8;
  int c  = threadIdx.x;
  for (int idx=c; idx<8*K; idx+=128){
    int r = idx / K, k = idx - r*K;
    xr[r][k] = x[(size_t)(i0+r)*xs + k];
  }
  __syncthreads();
  float acc[8] = {0,0,0,0,0,0,0,0};
  for (int k=0;k<K;k++){
    float w = W[k*NH + c];
    #pragma unroll
    for (int r=0;r<8;r++) acc[r] += xr[r][k]*w;
  }
  #pragma unroll
  for (int r=0;r<8;r++) xw[(size_t)(i0+r)*NH + c] = acc[r];
}

// acc[i,c] = xw[i,c] * dinv[i]^2   (self-loop term; also zero-initializes acc)
__global__ void k_selfinit(const float* __restrict__ xw, const float* __restrict__ dinv,
                           float* __restrict__ acc){
  int t = blockIdx.x*blockDim.x + threadIdx.x;
  int i = t >> 7;
  float dv = dinv[i];
  acc[t] = xw[t]*dv*dv;
}

// acc[dst,c] += xw[src,c]*coef[e]   (2 edges x 128 channels per block)
__global__ void k_scatter(const int* __restrict__ ei, const float* __restrict__ coef,
                          const float* __restrict__ xw, float* acc){
  int t = blockIdx.x*blockDim.x + threadIdx.x;
  int e = t >> 7, c = t & 127;
  int s = ei[e], d = ei[N_EDGES+e];
  atomicAdd(&acc[(size_t)d*NH + c], xw[(size_t)s*NH + c]*coef[e]);
}

// h[i, loff+c] = leaky_relu(acc[i,c] + b[c], 0.2)
__global__ void k_final(const float* __restrict__ acc, const float* __restrict__ b,
                        float* __restrict__ h, int loff){
  int t = blockIdx.x*blockDim.x + threadIdx.x;
  int i = t >> 7, c = t & 127;
  float v = acc[t] + b[c];
  h[(size_t)i*D3 + loff + c] = (v > 0.f) ? v : 0.2f*v;
}

// ---------- l2-normalize rows of h[8192x384] into f[:, 0:384] (stride 768) ----------
__global__ __launch_bounds__(128) void k_l2norm(const float* __restrict__ h, float* __restrict__ f){
  int i = blockIdx.x, t = threadIdx.x;
  float v0=h[(size_t)i*D3+t], v1=h[(size_t)i*D3+128+t], v2=h[(size_t)i*D3+256+t];
  float ss = v0*v0 + v1*v1 + v2*v2;
  #pragma unroll
  for (int o=32;o;o>>=1) ss += __shfl_down(ss,o,64);
  __shared__ float ws[2];
  if ((t&63)==0) ws[t>>6]=ss;
  __syncthreads();
  float scale = 1.0f/fmaxf(sqrtf(ws[0]+ws[1]), 1e-12f);
  f[(size_t)i*D6 + t]       = v0*scale;
  f[(size_t)i*D6 + 128 + t] = v1*scale;
  f[(size_t)i*D6 + 256 + t] = v2*scale;
}

// ---------- interaction: f_a[i, 384:768] = sum_{j in seg_b(g(i))} (a_i . b_j) b_j ----------
// block per node i (384 threads). mask is block-diagonal since batch is sorted.
__global__ __launch_bounds__(384) void k_interact(const float* __restrict__ fa,
                                                  const float* __restrict__ fb,
                                                  const int* __restrict__ batch_a,
                                                  const int* __restrict__ st_b,
                                                  float* __restrict__ fa_out){
  int i = blockIdx.x, t = threadIdx.x;
  float aval = fa[(size_t)i*D6 + t];   // cols 0:384 hold normalized vec
  int g  = batch_a[i];
  int j0 = st_b[g], j1 = st_b[g+1];
  __shared__ float wsum[2][6];
  int wid = t>>6, lane = t&63;
  float acc = 0.f;
  for (int j=j0; j<j1; j++){
    float v = fb[(size_t)j*D6 + t];
    float p = aval*v;
    #pragma unroll
    for (int o=32;o;o>>=1) p += __shfl_down(p,o,64);
    int buf = j & 1;
    if (lane==0) wsum[buf][wid] = p;
    __syncthreads();
    float dot = wsum[buf][0]+wsum[buf][1]+wsum[buf][2]+wsum[buf][3]+wsum[buf][4]+wsum[buf][5];
    acc += dot * v;
  }
  fa_out[(size_t)i*D6 + D3 + t] = acc;
}

// ---------- set2set ----------

// step 0 collapses: q_star=h=c=0 -> gates = bih+bhh (same for every segment)
__global__ void k_h0(const float* bih, const float* bhh, float* h0, float* c0){
  int j = threadIdx.x;  // 768
  float gi = bih[j]      + bhh[j];
  float gg = bih[2*D6+j] + bhh[2*D6+j];
  float go = bih[3*D6+j] + bhh[3*D6+j];
  float c = sigf(gi)*tanhf(gg);          // forget*0 drops
  c0[j] = c;
  h0[j] = sigf(go)*tanhf(c);
}

// cvec[j] = h0 . (Wih[j, 0:768] + Whh[j, :]) + bih[j] + bhh[j]
__global__ __launch_bounds__(256) void k_cvec(const float* __restrict__ Wih,
                                              const float* __restrict__ Whh,
                                              const float* bih, const float* bhh,
                                              const float* __restrict__ h0,
                                              float* __restrict__ cvec){
  __shared__ float hs[D6];
  int j = blockIdx.x*256 + threadIdx.x;   // 0..3071
  for (int k=threadIdx.x;k<D6;k+=256) hs[k]=h0[k];
  __syncthreads();
  const float* wi = Wih + (size_t)j*(2*D6);
  const float* wh = Whh + (size_t)j*D6;
  float acc = bih[j]+bhh[j];
  for (int k=0;k<D6;k++) acc += hs[k]*(wi[k]+wh[k]);
  cvec[j]=acc;
}

// e[n] = x[n,:] . hv   (hv = h0 shared, or per-segment row)
__global__ __launch_bounds__(256) void k_e(const float* __restrict__ x, const float* __restrict__ hbase,
                                           const int* __restrict__ batch, int perseg,
                                           float* __restrict__ e){
  int n = blockIdx.x, t = threadIdx.x;
  const float* hv = hbase + (perseg ? (size_t)batch[n]*D6 : 0);
  float s = 0;
  for (int c=t;c<D6;c+=256) s += x[(size_t)n*D6+c]*hv[c];
  #pragma unroll
  for (int o=32;o;o>>=1) s += __shfl_down(s,o,64);
  __shared__ float ws[4];
  if ((t&63)==0) ws[t>>6]=s;
  __syncthreads();
  if (t==0) e[n]=ws[0]+ws[1]+ws[2]+ws[3];
}

// segment softmax: a[n] = exp(e-emax)/sum  (one wave per segment)
__global__ __launch_bounds__(64) void k_attn(const float* __restrict__ e, const int* __restrict__ st,
                                             float* __restrict__ a){
  int g = blockIdx.x, t = threadIdx.x;
  int n0 = st[g], n1 = st[g+1];
  float m = -INFINITY;
  for (int n=n0+t;n<n1;n+=64) m = fmaxf(m, e[n]);
  #pragma unroll
  for (int o=32;o;o>>=1) m = fmaxf(m, __shfl_down(m,o,64));
  m = __shfl(m, 0, 64);
  float s = 0;
  for (int n=n0+t;n<n1;n+=64) s += __expf(e[n]-m);
  #pragma unroll
  for (int o=32;o;o>>=1) s += __shfl_down(s,o,64);
  s = __shfl(s, 0, 64);
  float inv = 1.0f/s;
  for (int n=n0+t;n<n1;n+=64) a[n] = __expf(e[n]-m)*inv;
}

// r[g, :] = sum_{n in seg} a[n]*x[n,:]  -> dst + g*dstride (caller pre-offsets dst)
__global__ __launch_bounds__(256) void k_r(const float* __restrict__ x, const float* __restrict__ a,
                                           const int* __restrict__ st, float* __restrict__ dst,
                                           int dstride){
  int g = blockIdx.x, t = threadIdx.x;
  int n0 = st[g], n1 = st[g+1];
  float a0=0,a1=0,a2=0;
  for (int n=n0;n<n1;n++){
    float av = a[n];
    const float* xr = x + (size_t)n*D6;
    a0 += av*xr[t]; a1 += av*xr[256+t]; a2 += av*xr[512+t];
  }
  float* d = dst + (size_t)g*dstride;
  d[t]=a0; d[256+t]=a1; d[512+t]=a2;
}

// gates[512x3072] = A[512x768] @ WihR^T + cvec ; WihR rows at B[n*1536 + k]
__global__ __launch_bounds__(256) void k_gemm_qs(const float* __restrict__ A,
                                                 const float* __restrict__ B,
                                                 const float* __restrict__ cv,
                                                 float* __restrict__ C){
  const int N=3072, K=D6, LDB=2*D6;
  __shared__ float As[16][68];
  __shared__ float Bs[16][68];
  int bm = blockIdx.y*64, bn = blockIdx.x*64;
  int t = threadIdx.x;
  int tx = t & 15, ty = t >> 4;
  float acc[4][4] = {};
  for (int k0=0; k0<K; k0+=16){
    for (int l=t; l<64*16; l+=256){
      int m = l >> 4, k = l & 15;
      As[k][m] = A[(size_t)(bm+m)*K   + k0 + k];
      Bs[k][m] = B[(size_t)(bn+m)*LDB + k0 + k];
    }
    __syncthreads();
    #pragma unroll
    for (int k=0;k<16;k++){
      float4 av = *(const float4*)&As[k][ty*4];
      float4 bv = *(const float4*)&Bs[k][tx*4];
      float a4[4]={av.x,av.y,av.z,av.w};
      float b4[4]={bv.x,bv.y,bv.z,bv.w};
      #pragma unroll
      for (int i=0;i<4;i++)
        #pragma unroll
        for (int j=0;j<4;j++) acc[i][j] += a4[i]*b4[j];
    }
    __syncthreads();
  }
  #pragma unroll
  for (int i=0;i<4;i++)
    #pragma unroll
    for (int j=0;j<4;j++){
      int m = bm + ty*4 + i, n = bn + tx*4 + j;
      C[(size_t)m*N + n] = acc[i][j] + cv[n];
    }
}

// LSTM step 1 pointwise; writes h into h1s and into z's h-slot
__global__ void k_lstm1(const float* __restrict__ gates, const float* __restrict__ c0,
                        float* __restrict__ h1s, float* __restrict__ z){
  int t = blockIdx.x*blockDim.x + threadIdx.x;  // 512*768
  int m = t/D6, j = t - m*D6;
  const float* gr = gates + (size_t)m*4*D6;
  float gi = gr[j], gf = gr[D6+j], gg = gr[2*D6+j], go = gr[3*D6+j];
  float c = sigf(gf)*c0[j] + sigf(gi)*tanhf(gg);
  float h = sigf(go)*tanhf(c);
  h1s[t] = h;
  int side = m >> 8, g = m & 255;
  z[(size_t)g*3072 + side*1536 + j] = h;
}

// ---------- MLP ----------

__global__ __launch_bounds__(256) void k_p1(const float* __restrict__ z, const float* __restrict__ W,
                                            const float* __restrict__ b, float* __restrict__ out){
  __shared__ float zr[4][3072];  // 48 KB
  int m0 = blockIdx.x*4, t = threadIdx.x;
  for (int r=0;r<4;r++)
    for (int k=t;k<3072;k+=256) zr[r][k]=z[(size_t)(m0+r)*3072+k];
  __syncthreads();
  const float* w = W + (size_t)t*3072;
  float acc[4]={0,0,0,0};
  for (int k=0;k<3072;k++){
    float wv = w[k];
    #pragma unroll
    for (int r=0;r<4;r++) acc[r]+=zr[r][k]*wv;
  }
  #pragma unroll
  for (int r=0;r<4;r++) out[(size_t)(m0+r)*256+t]=fmaxf(acc[r]+b[t],0.f);
}

__global__ __launch_bounds__(128) void k_p2(const float* __restrict__ z1, const float* __restrict__ W,
                                            const float* b, float* __restrict__ z2){
  __shared__ float zr[256];
  int m=blockIdx.x, t=threadIdx.x;
  for (int k=t;k<256;k+=128) zr[k]=z1[m*256+k];
  __syncthreads();
  const float* w = W + t*256;
  float acc=b[t];
  for (int k=0;k<256;k++) acc+=zr[k]*w[k];
  z2[m*128+t]=fmaxf(acc,0.f);
}

__global__ __launch_bounds__(128) void k_p3(const float* __restrict__ z2, const float* __restrict__ W,
                                            const float* b, float* __restrict__ out){
  int m=blockIdx.x, t=threadIdx.x;
  float p = z2[m*128+t]*W[t];
  #pragma unroll
  for (int o=32;o;o>>=1) p += __shfl_down(p,o,64);
  __shared__ float ws[2];
  if ((t&63)==0) ws[t>>6]=p;
  __syncthreads();
  if (t==0){ float v = ws[0]+ws[1]+b[0]; out[m]=1.0f/(1.0f+__expf(-v)); }
}

// ---------- launch ----------

extern "C" void kernel_launch(void* const* d_in, const int* in_sizes, int n_in,
                              void* d_out, int out_size, void* d_ws, size_t ws_size,
                              hipStream_t stream){
  const float* feat1=(const float*)d_in[0];
  const float* feat2=(const float*)d_in[1];
  const float* ea1  =(const float*)d_in[2];
  const float* ea2  =(const float*)d_in[3];
  const float* W0=(const float*)d_in[4];  const float* b0=(const float*)d_in[5];
  const float* W1=(const float*)d_in[6];  const float* b1=(const float*)d_in[7];
  const float* W2=(const float*)d_in[8];  const float* b2=(const float*)d_in[9];
  const float* Wih=(const float*)d_in[10]; const float* bih=(const float*)d_in[11];
  const float* Whh=(const float*)d_in[12]; const float* bhh=(const float*)d_in[13];
  const float* Wp1=(const float*)d_in[14]; const float* bp1=(const float*)d_in[15];
  const float* Wp2=(const float*)d_in[16]; const float* bp2=(const float*)d_in[17];
  const float* Wp3=(const float*)d_in[18]; const float* bp3=(const float*)d_in[19];
  const int* ei1=(const int*)d_in[20]; const int* ei2=(const int*)d_in[21];
  const int* batch1=(const int*)d_in[22]; const int* batch2=(const int*)d_in[23];
  float* out = (float*)d_out;

  float* base = (float*)d_ws;
  size_t off = 0;
  auto alloc = [&](size_t n)->float* { float* r = base + off; off += (n + 255) & ~(size_t)255; return r; };
  float* deg1 = alloc(N_NODES);          float* deg2 = alloc(N_NODES);
  float* coef1= alloc(N_EDGES);          float* coef2= alloc(N_EDGES);
  float* xw   = alloc((size_t)N_NODES*NH);
  float* accb = alloc((size_t)N_NODES*NH);
  float* h1   = alloc((size_t)N_NODES*D3);
  float* h2   = alloc((size_t)N_NODES*D3);
  float* f1   = alloc((size_t)N_NODES*D6);
  float* f2   = alloc((size_t)N_NODES*D6);
  float* h0   = alloc(D6);  float* c0 = alloc(D6);  float* cvec = alloc(4*D6);
  float* ebuf = alloc(N_NODES);  float* abuf = alloc(N_NODES);
  float* Abuf = alloc((size_t)512*D6);
  float* gates= alloc((size_t)512*4*D6);
  float* h1s  = alloc((size_t)512*D6);
  float* zbuf = alloc((size_t)256*3072);
  float* z1   = alloc((size_t)256*256);
  float* z2b  = alloc((size_t)256*128);
  int* cnt1 = (int*)alloc(NB);   int* cnt2 = (int*)alloc(NB);
  int* st1  = (int*)alloc(NB+1); int* st2  = (int*)alloc(NB+1);
  (void)ws_size; (void)in_sizes; (void)n_in; (void)out_size;

  k_init <<<32,256,0,stream>>>(deg1,deg2,cnt1,cnt2);
  k_deg  <<<512,256,0,stream>>>(ei1,ea1,deg1);
  k_deg  <<<512,256,0,stream>>>(ei2,ea2,deg2);
  k_count<<<32,256,0,stream>>>(batch1,batch2,cnt1,cnt2);
  k_dinv <<<32,256,0,stream>>>(deg1,deg2);
  k_scan <<<1,64,0,stream>>>(cnt1,cnt2,st1,st2);
  k_coef <<<512,256,0,stream>>>(ei1,ea1,deg1,coef1);
  k_coef <<<512,256,0,stream>>>(ei2,ea2,deg2,coef2);

  const float* Ws[3]={W0,W1,W2}; const float* bs[3]={b0,b1,b2};
  for (int side=0; side<2; side++){
    const float* feat = side? feat2:feat1;
    const int*   ei   = side? ei2:ei1;
    const float* coef = side? coef2:coef1;
    const float* dinv = side? deg2:deg1;
    float* h          = side? h2:h1;
    for (int l=0;l<3;l++){
      const float* x = (l==0)? feat : (h + (l-1)*NH);
      int xs = (l==0)? 64 : D3;
      int K  = (l==0)? 64 : NH;
      k_xw      <<<1024,128,0,stream>>>(x,xs,K,Ws[l],xw);
      k_selfinit<<<4096,256,0,stream>>>(xw,dinv,accb);
      k_scatter <<<65536,256,0,stream>>>(ei,coef,xw,accb);
      k_final   <<<4096,256,0,stream>>>(accb,bs[l],h,l*NH);
    }
  }

  k_l2norm<<<8192,128,0,stream>>>(h1,f1);
  k_l2norm<<<8192,128,0,stream>>>(h2,f2);
  k_interact<<<8192,384,0,stream>>>(f1,f2,batch1,st2,f1);
  k_interact<<<8192,384,0,stream>>>(f2,f1,batch2,st1,f2);

  k_h0  <<<1,768,0,stream>>>(bih,bhh,h0,c0);
  k_cvec<<<12,256,0,stream>>>(Wih,Whh,bih,bhh,h0,cvec);
  for (int side=0; side<2; side++){
    const float* f = side? f2:f1;
    const int* batch = side? batch2:batch1;
    const int* st    = side? st2:st1;
    k_e   <<<8192,256,0,stream>>>(f,h0,batch,0,ebuf);
    k_attn<<<256,64,0,stream>>>(ebuf,st,abuf);
    k_r   <<<256,256,0,stream>>>(f,abuf,st,Abuf + (size_t)side*256*D6, D6);
  }
  k_gemm_qs<<<dim3(48,8),256,0,stream>>>(Abuf, Wih+D6, cvec, gates);
  k_lstm1  <<<1536,256,0,stream>>>(gates,c0,h1s,zbuf);
  for (int side=0; side<2; side++){
    const float* f = side? f2:f1;
    const int* batch = side? batch2:batch1;
    const int* st    = side? st2:st1;
    k_e   <<<8192,256,0,stream>>>(f,h1s + (size_t)side*256*D6,batch,1,ebuf);
    k_attn<<<256,64,0,stream>>>(ebuf,st,abuf);
    k_r   <<<256,256,0,stream>>>(f,abuf,st, zbuf + side*1536 + 768, 3072);
  }

  k_p1<<<64,256,0,stream>>>(zbuf,Wp1,bp1,z1);
  k_p2<<<256,128,0,stream>>>(z1,Wp2,bp2,z2b);
  k_p3<<<256,128,0,stream>>>(z2b,Wp3,bp3,out);
}

// Round 2
// 876.073 us; speedup vs baseline: 1.7791x; 1.7791x over previous
//
#include <hip/hip_runtime.h>
#include <cmath>

#define N_NODES 8192
#define N_EDGES 131072
#define NB      256
#define NH      128
#define D3      384
#define D6      768

__device__ __forceinline__ float sigf(float x){ return 1.0f/(1.0f+__expf(-x)); }

// ---------- setup ----------

__global__ void k_init(float* deg1, float* deg2, int* ecnt1, int* ecnt2, int* cnt1, int* cnt2){
  int t = blockIdx.x*blockDim.x + threadIdx.x;
  if (t < N_NODES){ deg1[t]=1.f; deg2[t]=1.f; ecnt1[t]=0; ecnt2[t]=0; }
  if (t < NB){ cnt1[t]=0; cnt2[t]=0; }
}

// degree (weighted) + in-edge count, both sides in one launch
__global__ void k_deg(const int* __restrict__ ei1, const float* __restrict__ ea1, float* deg1, int* ecnt1,
                      const int* __restrict__ ei2, const float* __restrict__ ea2, float* deg2, int* ecnt2){
  int idx = blockIdx.x*blockDim.x + threadIdx.x;
  int side = idx >= N_EDGES;
  int e = idx & (N_EDGES-1);
  const int* ei = side? ei2:ei1; const float* ea = side? ea2:ea1;
  float* deg = side? deg2:deg1;  int* ecnt = side? ecnt2:ecnt1;
  int d = ei[N_EDGES+e];
  atomicAdd(&deg[d], ea[e]);
  atomicAdd(&ecnt[d], 1);
}

__global__ void k_count(const int* __restrict__ b1, const int* __restrict__ b2, int* c1, int* c2){
  int t = blockIdx.x*blockDim.x + threadIdx.x;
  if (t < N_NODES){ atomicAdd(&c1[b1[t]],1); atomicAdd(&c2[b2[t]],1); }
}

__global__ void k_dinv(float* deg1, float* deg2){
  int t = blockIdx.x*blockDim.x + threadIdx.x;
  if (t < N_NODES){ deg1[t]=rsqrtf(deg1[t]); deg2[t]=rsqrtf(deg2[t]); }
}

__global__ void k_coef(const int* __restrict__ ei1, const float* __restrict__ ea1,
                       const float* __restrict__ d1, float* __restrict__ c1,
                       const int* __restrict__ ei2, const float* __restrict__ ea2,
                       const float* __restrict__ d2, float* __restrict__ c2){
  int idx = blockIdx.x*blockDim.x + threadIdx.x;
  int side = idx >= N_EDGES;
  int e = idx & (N_EDGES-1);
  const int* ei = side? ei2:ei1; const float* ea = side? ea2:ea1;
  const float* dinv = side? d2:d1; float* coef = side? c2:c1;
  coef[e] = dinv[ei[e]]*ea[e]*dinv[ei[N_EDGES+e]];
}

// exclusive scan of per-node batch counts (256) -> segment starts; one block per side
__global__ __launch_bounds__(256) void k_scan256(const int* c1, const int* c2, int* s1, int* s2){
  const int* c = blockIdx.x? c2:c1; int* st = blockIdx.x? s2:s1;
  __shared__ int ps[256];
  int t = threadIdx.x;
  ps[t]=c[t]; __syncthreads();
  for (int d=1; d<256; d<<=1){
    int v = (t>=d)? ps[t-d]:0;
    __syncthreads();
    ps[t]+=v;
    __syncthreads();
  }
  st[t+1]=ps[t];
  if (t==0) st[0]=0;
}

// exclusive scan of in-edge counts (8192) -> CSR offsets + fill cursor; one block per side
__global__ __launch_bounds__(1024) void k_escan(const int* ec1, const int* ec2,
                                                int* off1, int* cur1, int* off2, int* cur2){
  const int* cnt = blockIdx.x? ec2:ec1;
  int* off = blockIdx.x? off2:off1;
  int* cur = blockIdx.x? cur2:cur1;
  __shared__ int ps[1024];
  int t = threadIdx.x;
  int base = t*8;
  int loc[8]; int s=0;
  #pragma unroll
  for (int k=0;k<8;k++){ loc[k]=s; s+=cnt[base+k]; }
  ps[t]=s; __syncthreads();
  for (int d=1; d<1024; d<<=1){
    int v = (t>=d)? ps[t-d]:0;
    __syncthreads();
    ps[t]+=v;
    __syncthreads();
  }
  int pre = (t==0)? 0 : ps[t-1];
  #pragma unroll
  for (int k=0;k<8;k++){ int v=pre+loc[k]; off[base+k]=v; cur[base+k]=v; }
  if (t==1023) off[N_NODES]=ps[1023];
}

// CSR fill: per edge, slot at dst; store src + coefficient
__global__ void k_fill(const int* __restrict__ ei1, const float* __restrict__ c1, int* cur1, int* es1, float* ec1,
                       const int* __restrict__ ei2, const float* __restrict__ c2, int* cur2, int* es2, float* ec2){
  int idx = blockIdx.x*blockDim.x + threadIdx.x;
  int side = idx >= N_EDGES;
  int e = idx & (N_EDGES-1);
  const int* ei = side? ei2:ei1; const float* coef = side? c2:c1;
  int* cur = side? cur2:cur1; int* es = side? es2:es1; float* ec = side? ec2:ec1;
  int d = ei[N_EDGES+e];
  int pos = atomicAdd(&cur[d], 1);
  es[pos] = ei[e];
  ec[pos] = coef[e];
}

// ---------- GCN ----------

// xw[i,c] = sum_k x[i,k]*W[k,c]; 8 rows/block, both sides in one grid
__global__ __launch_bounds__(128) void k_xw(const float* __restrict__ x1, const float* __restrict__ x2,
                                            int xs, int K, const float* __restrict__ W,
                                            float* __restrict__ xw1, float* __restrict__ xw2){
  __shared__ float xr[8][128];
  int blk = blockIdx.x;
  int side = blk >> 10; int b = blk & 1023;
  const float* x = side? x2:x1;
  float* xw = side? xw2:xw1;
  int i0 = b*8;
  int c = threadIdx.x;
  for (int idx=c; idx<8*K; idx+=128){
    int r = idx / K, k = idx - r*K;
    xr[r][k] = x[(size_t)(i0+r)*xs + k];
  }
  __syncthreads();
  float acc[8]={0,0,0,0,0,0,0,0};
  for (int k=0;k<K;k++){
    float w = W[k*NH+c];
    #pragma unroll
    for (int r=0;r<8;r++) acc[r]+=xr[r][k]*w;
  }
  #pragma unroll
  for (int r=0;r<8;r++) xw[(size_t)(i0+r)*NH+c]=acc[r];
}

// fused self-loop + CSR gather + bias + leaky, both sides
__global__ __launch_bounds__(128) void k_gather(const float* __restrict__ xw1, const float* __restrict__ xw2,
                                                const int* __restrict__ off1, const int* __restrict__ off2,
                                                const int* __restrict__ es1, const int* __restrict__ es2,
                                                const float* __restrict__ ec1, const float* __restrict__ ec2,
                                                const float* __restrict__ d1, const float* __restrict__ d2,
                                                const float* __restrict__ b,
                                                float* __restrict__ h1, float* __restrict__ h2, int loff){
  int blk = blockIdx.x;
  int side = blk >> 13; int i = blk & (N_NODES-1);
  const float* xw = side? xw2:xw1;
  const int* off = side? off2:off1;
  const int* es  = side? es2:es1;
  const float* ec= side? ec2:ec1;
  const float* dinv = side? d2:d1;
  float* h = side? h2:h1;
  int c = threadIdx.x;
  float dv = dinv[i];
  float acc = xw[(size_t)i*NH+c]*dv*dv;
  int r = off[i], r1 = off[i+1];
  for (; r+1<r1; r+=2){
    int s0=es[r], s1=es[r+1];
    float w0=ec[r], w1=ec[r+1];
    acc += xw[(size_t)s0*NH+c]*w0 + xw[(size_t)s1*NH+c]*w1;
  }
  if (r<r1) acc += xw[(size_t)es[r]*NH+c]*ec[r];
  float v = acc + b[c];
  h[(size_t)i*D3 + loff + c] = (v>0.f)? v : 0.2f*v;
}

// ---------- l2 normalize, both sides ----------
__global__ __launch_bounds__(128) void k_l2norm(const float* __restrict__ h1, const float* __restrict__ h2,
                                                float* __restrict__ f1, float* __restrict__ f2){
  int blk = blockIdx.x;
  int side = blk >> 13; int i = blk & (N_NODES-1);
  const float* h = side? h2:h1; float* f = side? f2:f1;
  int t = threadIdx.x;
  float v0=h[(size_t)i*D3+t], v1=h[(size_t)i*D3+128+t], v2=h[(size_t)i*D3+256+t];
  float ss = v0*v0+v1*v1+v2*v2;
  #pragma unroll
  for (int o=32;o;o>>=1) ss += __shfl_down(ss,o,64);
  __shared__ float ws[2];
  if ((t&63)==0) ws[t>>6]=ss;
  __syncthreads();
  float scale = 1.0f/fmaxf(sqrtf(ws[0]+ws[1]), 1e-12f);
  f[(size_t)i*D6+t]      =v0*scale;
  f[(size_t)i*D6+128+t]  =v1*scale;
  f[(size_t)i*D6+256+t]  =v2*scale;
}

// ---------- interaction ----------
// out_a[i,384:768] = sum_{j in seg_b} (a_i . b_j) b_j ; wave-parallel over j, no in-loop barriers
__global__ __launch_bounds__(384) void k_interact(const float* __restrict__ f1, const float* __restrict__ f2,
                                                  const int* __restrict__ batch1, const int* __restrict__ batch2,
                                                  const int* __restrict__ st1, const int* __restrict__ st2){
  int blk = blockIdx.x;
  int side = blk >> 13; int i = blk & (N_NODES-1);
  const float* fa = side? f2:f1;
  const float* fb = side? f1:f2;
  const int* ba   = side? batch2:batch1;
  const int* stb  = side? st1:st2;
  float* out = (float*)(side? f2:f1);
  int t = threadIdx.x;
  int w = t>>6, lane = t&63;
  const float* ar = fa + (size_t)i*D6;
  float a0=ar[lane], a1=ar[64+lane], a2=ar[128+lane], a3=ar[192+lane], a4=ar[256+lane], a5=ar[320+lane];
  int g = ba[i];
  int j0 = stb[g], j1 = stb[g+1];
  float r0=0,r1=0,r2=0,r3=0,r4=0,r5=0;
  for (int j=j0+w; j<j1; j+=6){
    const float* br = fb + (size_t)j*D6;
    float v0=br[lane], v1=br[64+lane], v2=br[128+lane], v3=br[192+lane], v4=br[256+lane], v5=br[320+lane];
    float p = a0*v0+a1*v1+a2*v2+a3*v3+a4*v4+a5*v5;
    #pragma unroll
    for (int m=1;m<64;m<<=1) p += __shfl_xor(p,m,64);
    r0+=p*v0; r1+=p*v1; r2+=p*v2; r3+=p*v3; r4+=p*v4; r5+=p*v5;
  }
  __shared__ float part[6][384];
  float* pw = &part[w][0];
  pw[lane]=r0; pw[64+lane]=r1; pw[128+lane]=r2; pw[192+lane]=r3; pw[256+lane]=r4; pw[320+lane]=r5;
  __syncthreads();
  float s = part[0][t]+part[1][t]+part[2][t]+part[3][t]+part[4][t]+part[5][t];
  out[(size_t)i*D6 + D3 + t] = s;
}

// ---------- set2set ----------

__global__ void k_h0(const float* bih, const float* bhh, float* h0, float* c0){
  int j = threadIdx.x;
  float gi = bih[j]      + bhh[j];
  float gg = bih[2*D6+j] + bhh[2*D6+j];
  float go = bih[3*D6+j] + bhh[3*D6+j];
  float c = sigf(gi)*tanhf(gg);
  c0[j]=c;
  h0[j]=sigf(go)*tanhf(c);
}

// cvec[j] = h0 . (Wih[j,0:768]+Whh[j,:]) + bih[j]+bhh[j]  (coalesced, one wave per j)
__global__ __launch_bounds__(64) void k_cvec(const float* __restrict__ Wih, const float* __restrict__ Whh,
                                             const float* bih, const float* bhh,
                                             const float* __restrict__ h0, float* __restrict__ cvec){
  int j = blockIdx.x, lane = threadIdx.x;
  const float* wi = Wih + (size_t)j*(2*D6);
  const float* wh = Whh + (size_t)j*D6;
  float acc=0;
  for (int k=lane;k<D6;k+=64) acc += h0[k]*(wi[k]+wh[k]);
  #pragma unroll
  for (int m=1;m<64;m<<=1) acc += __shfl_xor(acc,m,64);
  if (lane==0) cvec[j]=acc+bih[j]+bhh[j];
}

// e[n] = x[n,:] . hv ; both sides in one grid
__global__ __launch_bounds__(256) void k_e(const float* __restrict__ f1, const float* __restrict__ f2,
                                           const float* __restrict__ hbase, int perseg,
                                           const int* __restrict__ b1, const int* __restrict__ b2,
                                           float* __restrict__ e){
  int blk = blockIdx.x;
  int side = blk >> 13; int n = blk & (N_NODES-1);
  const float* x = side? f2:f1;
  const int* batch = side? b2:b1;
  const float* hv = hbase + (perseg? (size_t)(side*NB + batch[n])*D6 : 0);
  int t = threadIdx.x;
  float s = x[(size_t)n*D6+t]*hv[t] + x[(size_t)n*D6+256+t]*hv[256+t] + x[(size_t)n*D6+512+t]*hv[512+t];
  #pragma unroll
  for (int o=32;o;o>>=1) s += __shfl_down(s,o,64);
  __shared__ float ws[4];
  if ((t&63)==0) ws[t>>6]=s;
  __syncthreads();
  if (t==0) e[blk]=ws[0]+ws[1]+ws[2]+ws[3];
}

// segment softmax, both sides (512 segments total)
__global__ __launch_bounds__(64) void k_attn(const float* __restrict__ ebuf,
                                             const int* __restrict__ st1, const int* __restrict__ st2,
                                             float* __restrict__ abuf){
  int g = blockIdx.x & (NB-1), side = blockIdx.x >> 8;
  const int* st = side? st2:st1;
  const float* e = ebuf + side*N_NODES;
  float* a = abuf + side*N_NODES;
  int t = threadIdx.x;
  int n0=st[g], n1=st[g+1];
  float m=-INFINITY;
  for (int n=n0+t;n<n1;n+=64) m=fmaxf(m,e[n]);
  #pragma unroll
  for (int o=32;o;o>>=1) m=fmaxf(m,__shfl_down(m,o,64));
  m=__shfl(m,0,64);
  float s=0;
  for (int n=n0+t;n<n1;n+=64) s+=__expf(e[n]-m);
  #pragma unroll
  for (int o=32;o;o>>=1) s+=__shfl_down(s,o,64);
  s=__shfl(s,0,64);
  float inv=1.0f/s;
  for (int n=n0+t;n<n1;n+=64) a[n]=__expf(e[n]-m)*inv;
}

// r[g,:] = sum_n a[n]*x[n,:], both sides; dst = dst0 + side*sidestep + g*dstride
__global__ __launch_bounds__(256) void k_r(const float* __restrict__ f1, const float* __restrict__ f2,
                                           const float* __restrict__ abuf,
                                           const int* __restrict__ st1, const int* __restrict__ st2,
                                           float* __restrict__ dst0, long sidestep, int dstride){
  int g = blockIdx.x & (NB-1), side = blockIdx.x >> 8;
  const float* x = side? f2:f1;
  const int* st = side? st2:st1;
  const float* a = abuf + side*N_NODES;
  int t = threadIdx.x;
  int n0=st[g], n1=st[g+1];
  float a0=0,a1=0,a2=0;
  for (int n=n0;n<n1;n++){
    float av=a[n];
    const float* xr = x + (size_t)n*D6;
    a0+=av*xr[t]; a1+=av*xr[256+t]; a2+=av*xr[512+t];
  }
  float* d = dst0 + side*sidestep + (size_t)g*dstride;
  d[t]=a0; d[256+t]=a1; d[512+t]=a2;
}

// C[M x N] = A[M x K](lda) @ B[N x K](ldb)^T + cv[n]; act: 0=none, 1=relu
__global__ __launch_bounds__(256) void k_gemm(const float* __restrict__ A, int lda,
                                              const float* __restrict__ B, int ldb,
                                              const float* __restrict__ cv, float* __restrict__ C,
                                              int N, int K, int act){
  __shared__ float As[16][68];
  __shared__ float Bs[16][68];
  int bm = blockIdx.y*64, bn = blockIdx.x*64;
  int t = threadIdx.x;
  int tx = t & 15, ty = t >> 4;
  float acc[4][4] = {};
  for (int k0=0;k0<K;k0+=16){
    for (int l=t;l<64*16;l+=256){
      int m = l>>4, k = l&15;
      As[k][m] = A[(size_t)(bm+m)*lda + k0+k];
      Bs[k][m] = B[(size_t)(bn+m)*ldb + k0+k];
    }
    __syncthreads();
    #pragma unroll
    for (int k=0;k<16;k++){
      float4 av = *(const float4*)&As[k][ty*4];
      float4 bv = *(const float4*)&Bs[k][tx*4];
      float a4[4]={av.x,av.y,av.z,av.w};
      float b4[4]={bv.x,bv.y,bv.z,bv.w};
      #pragma unroll
      for (int i=0;i<4;i++)
        #pragma unroll
        for (int j=0;j<4;j++) acc[i][j]+=a4[i]*b4[j];
    }
    __syncthreads();
  }
  #pragma unroll
  for (int i=0;i<4;i++)
    #pragma unroll
    for (int j=0;j<4;j++){
      int m = bm+ty*4+i, n = bn+tx*4+j;
      float v = acc[i][j]+cv[n];
      if (act) v = fmaxf(v,0.f);
      C[(size_t)m*N+n]=v;
    }
}

__global__ void k_lstm1(const float* __restrict__ gates, const float* __restrict__ c0,
                        float* __restrict__ h1s, float* __restrict__ z){
  int t = blockIdx.x*blockDim.x + threadIdx.x;
  int m = t/D6, j = t - m*D6;
  const float* gr = gates + (size_t)m*4*D6;
  float gi=gr[j], gf=gr[D6+j], gg=gr[2*D6+j], go=gr[3*D6+j];
  float c = sigf(gf)*c0[j] + sigf(gi)*tanhf(gg);
  float h = sigf(go)*tanhf(c);
  h1s[t]=h;
  int side = m>>8, g = m&255;
  z[(size_t)g*3072 + side*1536 + j]=h;
}

__global__ __launch_bounds__(128) void k_p3(const float* __restrict__ z2, const float* __restrict__ W,
                                            const float* b, float* __restrict__ out){
  int m=blockIdx.x, t=threadIdx.x;
  float p = z2[m*128+t]*W[t];
  #pragma unroll
  for (int o=32;o;o>>=1) p += __shfl_down(p,o,64);
  __shared__ float ws[2];
  if ((t&63)==0) ws[t>>6]=p;
  __syncthreads();
  if (t==0){ float v=ws[0]+ws[1]+b[0]; out[m]=1.0f/(1.0f+__expf(-v)); }
}

// ---------- launch ----------

extern "C" void kernel_launch(void* const* d_in, const int* in_sizes, int n_in,
                              void* d_out, int out_size, void* d_ws, size_t ws_size,
                              hipStream_t stream){
  const float* feat1=(const float*)d_in[0];
  const float* feat2=(const float*)d_in[1];
  const float* ea1  =(const float*)d_in[2];
  const float* ea2  =(const float*)d_in[3];
  const float* W0=(const float*)d_in[4];  const float* b0=(const float*)d_in[5];
  const float* W1=(const float*)d_in[6];  const float* b1=(const float*)d_in[7];
  const float* W2=(const float*)d_in[8];  const float* b2=(const float*)d_in[9];
  const float* Wih=(const float*)d_in[10]; const float* bih=(const float*)d_in[11];
  const float* Whh=(const float*)d_in[12]; const float* bhh=(const float*)d_in[13];
  const float* Wp1=(const float*)d_in[14]; const float* bp1=(const float*)d_in[15];
  const float* Wp2=(const float*)d_in[16]; const float* bp2=(const float*)d_in[17];
  const float* Wp3=(const float*)d_in[18]; const float* bp3=(const float*)d_in[19];
  const int* ei1=(const int*)d_in[20]; const int* ei2=(const int*)d_in[21];
  const int* batch1=(const int*)d_in[22]; const int* batch2=(const int*)d_in[23];
  float* out = (float*)d_out;

  float* base = (float*)d_ws;
  size_t off = 0;
  auto alloc = [&](size_t n)->float* { float* r = base + off; off += (n + 255) & ~(size_t)255; return r; };
  float* deg1 = alloc(N_NODES);          float* deg2 = alloc(N_NODES);
  float* coef1= alloc(N_EDGES);          float* coef2= alloc(N_EDGES);
  float* xw1  = alloc((size_t)N_NODES*NH); float* xw2 = alloc((size_t)N_NODES*NH);
  float* h1   = alloc((size_t)N_NODES*D3);
  float* h2   = alloc((size_t)N_NODES*D3);
  float* f1   = alloc((size_t)N_NODES*D6);
  float* f2   = alloc((size_t)N_NODES*D6);
  float* ecoef1 = alloc(N_EDGES);        float* ecoef2 = alloc(N_EDGES);
  float* h0   = alloc(D6);  float* c0 = alloc(D6);  float* cvec = alloc(4*D6);
  float* ebuf = alloc(2*N_NODES);  float* abuf = alloc(2*N_NODES);
  float* Abuf = alloc((size_t)512*D6);
  float* gates= alloc((size_t)512*4*D6);
  float* h1s  = alloc((size_t)512*D6);
  float* zbuf = alloc((size_t)256*3072);
  float* z1   = alloc((size_t)256*256);
  float* z2b  = alloc((size_t)256*128);
  int* cnt1 = (int*)alloc(NB);   int* cnt2 = (int*)alloc(NB);
  int* st1  = (int*)alloc(NB+1); int* st2  = (int*)alloc(NB+1);
  int* ecnt1= (int*)alloc(N_NODES); int* ecnt2 = (int*)alloc(N_NODES);
  int* eoff1= (int*)alloc(N_NODES+1); int* eoff2 = (int*)alloc(N_NODES+1);
  int* ecur1= (int*)alloc(N_NODES); int* ecur2 = (int*)alloc(N_NODES);
  int* esrc1= (int*)alloc(N_EDGES); int* esrc2 = (int*)alloc(N_EDGES);
  (void)ws_size; (void)in_sizes; (void)n_in; (void)out_size;

  k_init   <<<32,256,0,stream>>>(deg1,deg2,ecnt1,ecnt2,cnt1,cnt2);
  k_deg    <<<1024,256,0,stream>>>(ei1,ea1,deg1,ecnt1, ei2,ea2,deg2,ecnt2);
  k_count  <<<32,256,0,stream>>>(batch1,batch2,cnt1,cnt2);
  k_dinv   <<<32,256,0,stream>>>(deg1,deg2);
  k_coef   <<<1024,256,0,stream>>>(ei1,ea1,deg1,coef1, ei2,ea2,deg2,coef2);
  k_scan256<<<2,256,0,stream>>>(cnt1,cnt2,st1,st2);
  k_escan  <<<2,1024,0,stream>>>(ecnt1,ecnt2,eoff1,ecur1,eoff2,ecur2);
  k_fill   <<<1024,256,0,stream>>>(ei1,coef1,ecur1,esrc1,ecoef1, ei2,coef2,ecur2,esrc2,ecoef2);

  const float* Ws[3]={W0,W1,W2}; const float* bs[3]={b0,b1,b2};
  for (int l=0;l<3;l++){
    const float* x1 = (l==0)? feat1 : (h1 + (l-1)*NH);
    const float* x2 = (l==0)? feat2 : (h2 + (l-1)*NH);
    int xs = (l==0)? 64 : D3;
    int K  = (l==0)? 64 : NH;
    k_xw    <<<2048,128,0,stream>>>(x1,x2,xs,K,Ws[l],xw1,xw2);
    k_gather<<<16384,128,0,stream>>>(xw1,xw2,eoff1,eoff2,esrc1,esrc2,ecoef1,ecoef2,
                                     deg1,deg2,bs[l],h1,h2,l*NH);
  }

  k_l2norm  <<<16384,128,0,stream>>>(h1,h2,f1,f2);
  k_interact<<<16384,384,0,stream>>>(f1,f2,batch1,batch2,st1,st2);

  k_h0  <<<1,768,0,stream>>>(bih,bhh,h0,c0);
  k_cvec<<<3072,64,0,stream>>>(Wih,Whh,bih,bhh,h0,cvec);

  // step-1 attention with shared h0
  k_e   <<<16384,256,0,stream>>>(f1,f2,h0,0,batch1,batch2,ebuf);
  k_attn<<<512,64,0,stream>>>(ebuf,st1,st2,abuf);
  k_r   <<<512,256,0,stream>>>(f1,f2,abuf,st1,st2,Abuf,(long)256*D6,D6);

  // gates = Abuf @ WihR^T + cvec  (M=512, N=3072, K=768)
  k_gemm <<<dim3(48,8),256,0,stream>>>(Abuf,D6, Wih+D6,2*D6, cvec, gates, 3072, D6, 0);
  k_lstm1<<<1536,256,0,stream>>>(gates,c0,h1s,zbuf);

  // step-2 attention with per-segment h
  k_e   <<<16384,256,0,stream>>>(f1,f2,h1s,1,batch1,batch2,ebuf);
  k_attn<<<512,64,0,stream>>>(ebuf,st1,st2,abuf);
  k_r   <<<512,256,0,stream>>>(f1,f2,abuf,st1,st2,zbuf+768,1536,3072);

  // MLP: z1 = relu(zbuf@Wp1^T+bp1); z2 = relu(z1@Wp2^T+bp2); out = sigmoid(z2@Wp3^T+bp3)
  k_gemm<<<dim3(4,4),256,0,stream>>>(zbuf,3072, Wp1,3072, bp1, z1, 256, 3072, 1);
  k_gemm<<<dim3(2,4),256,0,stream>>>(z1,256, Wp2,256, bp2, z2b, 128, 256, 1);
  k_p3  <<<256,128,0,stream>>>(z2b,Wp3,bp3,out);
}

// Round 3
// 540.718 us; speedup vs baseline: 2.8826x; 1.6202x over previous
//
#include <hip/hip_runtime.h>
#include <cmath>

#define N_NODES 8192
#define N_EDGES 131072
#define NB      256
#define NH      128
#define D3      384
#define D6      768

__device__ __forceinline__ float sigf(float x){ return 1.0f/(1.0f+__expf(-x)); }

// ---------- setup ----------

__global__ void k_init(float* deg1, float* deg2, int* ecnt1, int* ecnt2, int* cnt1, int* cnt2){
  int t = blockIdx.x*blockDim.x + threadIdx.x;
  if (t < N_NODES){ deg1[t]=1.f; deg2[t]=1.f; ecnt1[t]=0; ecnt2[t]=0; }
  if (t < NB){ cnt1[t]=0; cnt2[t]=0; }
}

__global__ void k_deg(const int* __restrict__ ei1, const float* __restrict__ ea1, float* deg1, int* ecnt1,
                      const int* __restrict__ ei2, const float* __restrict__ ea2, float* deg2, int* ecnt2){
  int idx = blockIdx.x*blockDim.x + threadIdx.x;
  int side = idx >= N_EDGES;
  int e = idx & (N_EDGES-1);
  const int* ei = side? ei2:ei1; const float* ea = side? ea2:ea1;
  float* deg = side? deg2:deg1;  int* ecnt = side? ecnt2:ecnt1;
  int d = ei[N_EDGES+e];
  atomicAdd(&deg[d], ea[e]);
  atomicAdd(&ecnt[d], 1);
}

__global__ void k_count(const int* __restrict__ b1, const int* __restrict__ b2, int* c1, int* c2){
  int t = blockIdx.x*blockDim.x + threadIdx.x;
  if (t < N_NODES){ atomicAdd(&c1[b1[t]],1); atomicAdd(&c2[b2[t]],1); }
}

__global__ void k_dinv(float* deg1, float* deg2){
  int t = blockIdx.x*blockDim.x + threadIdx.x;
  if (t < N_NODES){ deg1[t]=rsqrtf(deg1[t]); deg2[t]=rsqrtf(deg2[t]); }
}

__global__ void k_coef(const int* __restrict__ ei1, const float* __restrict__ ea1,
                       const float* __restrict__ d1, float* __restrict__ c1,
                       const int* __restrict__ ei2, const float* __restrict__ ea2,
                       const float* __restrict__ d2, float* __restrict__ c2){
  int idx = blockIdx.x*blockDim.x + threadIdx.x;
  int side = idx >= N_EDGES;
  int e = idx & (N_EDGES-1);
  const int* ei = side? ei2:ei1; const float* ea = side? ea2:ea1;
  const float* dinv = side? d2:d1; float* coef = side? c2:c1;
  coef[e] = dinv[ei[e]]*ea[e]*dinv[ei[N_EDGES+e]];
}

__global__ __launch_bounds__(256) void k_scan256(const int* c1, const int* c2, int* s1, int* s2){
  const int* c = blockIdx.x? c2:c1; int* st = blockIdx.x? s2:s1;
  __shared__ int ps[256];
  int t = threadIdx.x;
  ps[t]=c[t]; __syncthreads();
  for (int d=1; d<256; d<<=1){
    int v = (t>=d)? ps[t-d]:0;
    __syncthreads();
    ps[t]+=v;
    __syncthreads();
  }
  st[t+1]=ps[t];
  if (t==0) st[0]=0;
}

__global__ __launch_bounds__(1024) void k_escan(const int* ec1, const int* ec2,
                                                int* off1, int* cur1, int* off2, int* cur2){
  const int* cnt = blockIdx.x? ec2:ec1;
  int* off = blockIdx.x? off2:off1;
  int* cur = blockIdx.x? cur2:cur1;
  __shared__ int ps[1024];
  int t = threadIdx.x;
  int base = t*8;
  int loc[8]; int s=0;
  #pragma unroll
  for (int k=0;k<8;k++){ loc[k]=s; s+=cnt[base+k]; }
  ps[t]=s; __syncthreads();
  for (int d=1; d<1024; d<<=1){
    int v = (t>=d)? ps[t-d]:0;
    __syncthreads();
    ps[t]+=v;
    __syncthreads();
  }
  int pre = (t==0)? 0 : ps[t-1];
  #pragma unroll
  for (int k=0;k<8;k++){ int v=pre+loc[k]; off[base+k]=v; cur[base+k]=v; }
  if (t==1023) off[N_NODES]=ps[1023];
}

__global__ void k_fill(const int* __restrict__ ei1, const float* __restrict__ c1, int* cur1, int* es1, float* ec1,
                       const int* __restrict__ ei2, const float* __restrict__ c2, int* cur2, int* es2, float* ec2){
  int idx = blockIdx.x*blockDim.x + threadIdx.x;
  int side = idx >= N_EDGES;
  int e = idx & (N_EDGES-1);
  const int* ei = side? ei2:ei1; const float* coef = side? c2:c1;
  int* cur = side? cur2:cur1; int* es = side? es2:es1; float* ec = side? ec2:ec1;
  int d = ei[N_EDGES+e];
  int pos = atomicAdd(&cur[d], 1);
  es[pos] = ei[e];
  ec[pos] = coef[e];
}

// ---------- GCN ----------

__global__ __launch_bounds__(128) void k_xw(const float* __restrict__ x1, const float* __restrict__ x2,
                                            int xs, int K, const float* __restrict__ W,
                                            float* __restrict__ xw1, float* __restrict__ xw2){
  __shared__ float xr[8][128];
  int blk = blockIdx.x;
  int side = blk >> 10; int b = blk & 1023;
  const float* x = side? x2:x1;
  float* xw = side? xw2:xw1;
  int i0 = b*8;
  int c = threadIdx.x;
  for (int idx=c; idx<8*K; idx+=128){
    int r = idx / K, k = idx - r*K;
    xr[r][k] = x[(size_t)(i0+r)*xs + k];
  }
  __syncthreads();
  float acc[8]={0,0,0,0,0,0,0,0};
  for (int k=0;k<K;k++){
    float w = W[k*NH+c];
    #pragma unroll
    for (int r=0;r<8;r++) acc[r]+=xr[r][k]*w;
  }
  #pragma unroll
  for (int r=0;r<8;r++) xw[(size_t)(i0+r)*NH+c]=acc[r];
}

__global__ __launch_bounds__(128) void k_gather(const float* __restrict__ xw1, const float* __restrict__ xw2,
                                                const int* __restrict__ off1, const int* __restrict__ off2,
                                                const int* __restrict__ es1, const int* __restrict__ es2,
                                                const float* __restrict__ ec1, const float* __restrict__ ec2,
                                                const float* __restrict__ d1, const float* __restrict__ d2,
                                                const float* __restrict__ b,
                                                float* __restrict__ h1, float* __restrict__ h2, int loff){
  int blk = blockIdx.x;
  int side = blk >> 13; int i = blk & (N_NODES-1);
  const float* xw = side? xw2:xw1;
  const int* off = side? off2:off1;
  const int* es  = side? es2:es1;
  const float* ec= side? ec2:ec1;
  const float* dinv = side? d2:d1;
  float* h = side? h2:h1;
  int c = threadIdx.x;
  float dv = dinv[i];
  float acc = xw[(size_t)i*NH+c]*dv*dv;
  int r = off[i], r1 = off[i+1];
  for (; r+1<r1; r+=2){
    int s0=es[r], s1=es[r+1];
    float w0=ec[r], w1=ec[r+1];
    acc += xw[(size_t)s0*NH+c]*w0 + xw[(size_t)s1*NH+c]*w1;
  }
  if (r<r1) acc += xw[(size_t)es[r]*NH+c]*ec[r];
  float v = acc + b[c];
  h[(size_t)i*D3 + loff + c] = (v>0.f)? v : 0.2f*v;
}

// ---------- l2 normalize ----------
__global__ __launch_bounds__(128) void k_l2norm(const float* __restrict__ h1, const float* __restrict__ h2,
                                                float* __restrict__ f1, float* __restrict__ f2){
  int blk = blockIdx.x;
  int side = blk >> 13; int i = blk & (N_NODES-1);
  const float* h = side? h2:h1; float* f = side? f2:f1;
  int t = threadIdx.x;
  float v0=h[(size_t)i*D3+t], v1=h[(size_t)i*D3+128+t], v2=h[(size_t)i*D3+256+t];
  float ss = v0*v0+v1*v1+v2*v2;
  #pragma unroll
  for (int o=32;o;o>>=1) ss += __shfl_down(ss,o,64);
  __shared__ float ws[2];
  if ((t&63)==0) ws[t>>6]=ss;
  __syncthreads();
  float scale = 1.0f/fmaxf(sqrtf(ws[0]+ws[1]), 1e-12f);
  f[(size_t)i*D6+t]      =v0*scale;
  f[(size_t)i*D6+128+t]  =v1*scale;
  f[(size_t)i*D6+256+t]  =v2*scale;
}

// ---------- interaction ----------
__global__ __launch_bounds__(384) void k_interact(const float* __restrict__ f1, const float* __restrict__ f2,
                                                  const int* __restrict__ batch1, const int* __restrict__ batch2,
                                                  const int* __restrict__ st1, const int* __restrict__ st2){
  int blk = blockIdx.x;
  int side = blk >> 13; int i = blk & (N_NODES-1);
  const float* fa = side? f2:f1;
  const float* fb = side? f1:f2;
  const int* ba   = side? batch2:batch1;
  const int* stb  = side? st1:st2;
  float* out = (float*)(side? f2:f1);
  int t = threadIdx.x;
  int w = t>>6, lane = t&63;
  const float* ar = fa + (size_t)i*D6;
  float a0=ar[lane], a1=ar[64+lane], a2=ar[128+lane], a3=ar[192+lane], a4=ar[256+lane], a5=ar[320+lane];
  int g = ba[i];
  int j0 = stb[g], j1 = stb[g+1];
  float r0=0,r1=0,r2=0,r3=0,r4=0,r5=0;
  for (int j=j0+w; j<j1; j+=6){
    const float* br = fb + (size_t)j*D6;
    float v0=br[lane], v1=br[64+lane], v2=br[128+lane], v3=br[192+lane], v4=br[256+lane], v5=br[320+lane];
    float p = a0*v0+a1*v1+a2*v2+a3*v3+a4*v4+a5*v5;
    #pragma unroll
    for (int m=1;m<64;m<<=1) p += __shfl_xor(p,m,64);
    r0+=p*v0; r1+=p*v1; r2+=p*v2; r3+=p*v3; r4+=p*v4; r5+=p*v5;
  }
  __shared__ float part[6][384];
  float* pw = &part[w][0];
  pw[lane]=r0; pw[64+lane]=r1; pw[128+lane]=r2; pw[192+lane]=r3; pw[256+lane]=r4; pw[320+lane]=r5;
  __syncthreads();
  float s = part[0][t]+part[1][t]+part[2][t]+part[3][t]+part[4][t]+part[5][t];
  out[(size_t)i*D6 + D3 + t] = s;
}

// ---------- set2set ----------

__global__ void k_h0(const float* bih, const float* bhh, float* h0, float* c0){
  int j = threadIdx.x;
  float gi = bih[j]      + bhh[j];
  float gg = bih[2*D6+j] + bhh[2*D6+j];
  float go = bih[3*D6+j] + bhh[3*D6+j];
  float c = sigf(gi)*tanhf(gg);
  c0[j]=c;
  h0[j]=sigf(go)*tanhf(c);
}

__global__ __launch_bounds__(64) void k_cvec(const float* __restrict__ Wih, const float* __restrict__ Whh,
                                             const float* bih, const float* bhh,
                                             const float* __restrict__ h0, float* __restrict__ cvec){
  int j = blockIdx.x, lane = threadIdx.x;
  const float* wi = Wih + (size_t)j*(2*D6);
  const float* wh = Whh + (size_t)j*D6;
  float acc=0;
  for (int k=lane;k<D6;k+=64) acc += h0[k]*(wi[k]+wh[k]);
  #pragma unroll
  for (int m=1;m<64;m<<=1) acc += __shfl_xor(acc,m,64);
  if (lane==0) cvec[j]=acc+bih[j]+bhh[j];
}

__global__ __launch_bounds__(256) void k_e(const float* __restrict__ f1, const float* __restrict__ f2,
                                           const float* __restrict__ hbase, int perseg,
                                           const int* __restrict__ b1, const int* __restrict__ b2,
                                           float* __restrict__ e){
  int blk = blockIdx.x;
  int side = blk >> 13; int n = blk & (N_NODES-1);
  const float* x = side? f2:f1;
  const int* batch = side? b2:b1;
  const float* hv = hbase + (perseg? (size_t)(side*NB + batch[n])*D6 : 0);
  int t = threadIdx.x;
  float s = x[(size_t)n*D6+t]*hv[t] + x[(size_t)n*D6+256+t]*hv[256+t] + x[(size_t)n*D6+512+t]*hv[512+t];
  #pragma unroll
  for (int o=32;o;o>>=1) s += __shfl_down(s,o,64);
  __shared__ float ws[4];
  if ((t&63)==0) ws[t>>6]=s;
  __syncthreads();
  if (t==0) e[blk]=ws[0]+ws[1]+ws[2]+ws[3];
}

__global__ __launch_bounds__(64) void k_attn(const float* __restrict__ ebuf,
                                             const int* __restrict__ st1, const int* __restrict__ st2,
                                             float* __restrict__ abuf){
  int g = blockIdx.x & (NB-1), side = blockIdx.x >> 8;
  const int* st = side? st2:st1;
  const float* e = ebuf + side*N_NODES;
  float* a = abuf + side*N_NODES;
  int t = threadIdx.x;
  int n0=st[g], n1=st[g+1];
  float m=-INFINITY;
  for (int n=n0+t;n<n1;n+=64) m=fmaxf(m,e[n]);
  #pragma unroll
  for (int o=32;o;o>>=1) m=fmaxf(m,__shfl_down(m,o,64));
  m=__shfl(m,0,64);
  float s=0;
  for (int n=n0+t;n<n1;n+=64) s+=__expf(e[n]-m);
  #pragma unroll
  for (int o=32;o;o>>=1) s+=__shfl_down(s,o,64);
  s=__shfl(s,0,64);
  float inv=1.0f/s;
  for (int n=n0+t;n<n1;n+=64) a[n]=__expf(e[n]-m)*inv;
}

__global__ __launch_bounds__(256) void k_r(const float* __restrict__ f1, const float* __restrict__ f2,
                                           const float* __restrict__ abuf,
                                           const int* __restrict__ st1, const int* __restrict__ st2,
                                           float* __restrict__ dst0, long sidestep, int dstride){
  int g = blockIdx.x & (NB-1), side = blockIdx.x >> 8;
  const float* x = side? f2:f1;
  const int* st = side? st2:st1;
  const float* a = abuf + side*N_NODES;
  int t = threadIdx.x;
  int n0=st[g], n1=st[g+1];
  float a0=0,a1=0,a2=0;
  for (int n=n0;n<n1;n++){
    float av=a[n];
    const float* xr = x + (size_t)n*D6;
    a0+=av*xr[t]; a1+=av*xr[256+t]; a2+=av*xr[512+t];
  }
  float* d = dst0 + side*sidestep + (size_t)g*dstride;
  d[t]=a0; d[256+t]=a1; d[512+t]=a2;
}

// split-K GEMM: partial[s][M x N] = A[M x K-chunk] @ B^T-chunk ; s = blockIdx.z
__global__ __launch_bounds__(256) void k_gemm_sk(const float* __restrict__ A, int lda,
                                                 const float* __restrict__ B, int ldb,
                                                 float* __restrict__ partial,
                                                 int M, int N, int kchunk){
  __shared__ float As[16][68];
  __shared__ float Bs[16][68];
  int bm = blockIdx.y*64, bn = blockIdx.x*64;
  int kbase = blockIdx.z*kchunk;
  int t = threadIdx.x;
  int tx = t & 15, ty = t >> 4;
  float acc[4][4] = {};
  for (int k0=kbase;k0<kbase+kchunk;k0+=16){
    for (int l=t;l<64*16;l+=256){
      int m = l>>4, k = l&15;
      As[k][m] = A[(size_t)(bm+m)*lda + k0+k];
      Bs[k][m] = B[(size_t)(bn+m)*ldb + k0+k];
    }
    __syncthreads();
    #pragma unroll
    for (int k=0;k<16;k++){
      float4 av = *(const float4*)&As[k][ty*4];
      float4 bv = *(const float4*)&Bs[k][tx*4];
      float a4[4]={av.x,av.y,av.z,av.w};
      float b4[4]={bv.x,bv.y,bv.z,bv.w};
      #pragma unroll
      for (int i=0;i<4;i++)
        #pragma unroll
        for (int j=0;j<4;j++) acc[i][j]+=a4[i]*b4[j];
    }
    __syncthreads();
  }
  float* pout = partial + (size_t)blockIdx.z*M*N;
  #pragma unroll
  for (int i=0;i<4;i++)
    #pragma unroll
    for (int j=0;j<4;j++){
      int m = bm+ty*4+i, n = bn+tx*4+j;
      pout[(size_t)m*N+n]=acc[i][j];
    }
}

// dst[m,n] = act( sum_s partial[s][m,n] + cv[n] )
__global__ __launch_bounds__(256) void k_reduce(const float* __restrict__ partial, int S, long MN,
                                                const float* __restrict__ cv, float* __restrict__ dst,
                                                int N, int act){
  long idx = (long)blockIdx.x*256 + threadIdx.x;
  if (idx >= MN) return;
  float s = 0;
  for (int p=0;p<S;p++) s += partial[(size_t)p*MN + idx];
  s += cv[idx % N];
  if (act) s = fmaxf(s,0.f);
  dst[idx]=s;
}

__global__ void k_lstm1(const float* __restrict__ gates, const float* __restrict__ c0,
                        float* __restrict__ h1s, float* __restrict__ z){
  int t = blockIdx.x*blockDim.x + threadIdx.x;
  int m = t/D6, j = t - m*D6;
  const float* gr = gates + (size_t)m*4*D6;
  float gi=gr[j], gf=gr[D6+j], gg=gr[2*D6+j], go=gr[3*D6+j];
  float c = sigf(gf)*c0[j] + sigf(gi)*tanhf(gg);
  float h = sigf(go)*tanhf(c);
  h1s[t]=h;
  int side = m>>8, g = m&255;
  z[(size_t)g*3072 + side*1536 + j]=h;
}

__global__ __launch_bounds__(128) void k_p3(const float* __restrict__ z2, const float* __restrict__ W,
                                            const float* b, float* __restrict__ out){
  int m=blockIdx.x, t=threadIdx.x;
  float p = z2[m*128+t]*W[t];
  #pragma unroll
  for (int o=32;o;o>>=1) p += __shfl_down(p,o,64);
  __shared__ float ws[2];
  if ((t&63)==0) ws[t>>6]=p;
  __syncthreads();
  if (t==0){ float v=ws[0]+ws[1]+b[0]; out[m]=1.0f/(1.0f+__expf(-v)); }
}

// ---------- launch ----------

extern "C" void kernel_launch(void* const* d_in, const int* in_sizes, int n_in,
                              void* d_out, int out_size, void* d_ws, size_t ws_size,
                              hipStream_t stream){
  const float* feat1=(const float*)d_in[0];
  const float* feat2=(const float*)d_in[1];
  const float* ea1  =(const float*)d_in[2];
  const float* ea2  =(const float*)d_in[3];
  const float* W0=(const float*)d_in[4];  const float* b0=(const float*)d_in[5];
  const float* W1=(const float*)d_in[6];  const float* b1=(const float*)d_in[7];
  const float* W2=(const float*)d_in[8];  const float* b2=(const float*)d_in[9];
  const float* Wih=(const float*)d_in[10]; const float* bih=(const float*)d_in[11];
  const float* Whh=(const float*)d_in[12]; const float* bhh=(const float*)d_in[13];
  const float* Wp1=(const float*)d_in[14]; const float* bp1=(const float*)d_in[15];
  const float* Wp2=(const float*)d_in[16]; const float* bp2=(const float*)d_in[17];
  const float* Wp3=(const float*)d_in[18]; const float* bp3=(const float*)d_in[19];
  const int* ei1=(const int*)d_in[20]; const int* ei2=(const int*)d_in[21];
  const int* batch1=(const int*)d_in[22]; const int* batch2=(const int*)d_in[23];
  float* out = (float*)d_out;

  float* base = (float*)d_ws;
  size_t off = 0;
  auto alloc = [&](size_t n)->float* { float* r = base + off; off += (n + 255) & ~(size_t)255; return r; };
  float* deg1 = alloc(N_NODES);          float* deg2 = alloc(N_NODES);
  float* coef1= alloc(N_EDGES);          float* coef2= alloc(N_EDGES);
  float* xw1  = alloc((size_t)N_NODES*NH); float* xw2 = alloc((size_t)N_NODES*NH);
  float* h1   = alloc((size_t)N_NODES*D3);
  float* h2   = alloc((size_t)N_NODES*D3);
  float* f1   = alloc((size_t)N_NODES*D6);
  float* f2   = alloc((size_t)N_NODES*D6);
  float* ecoef1 = alloc(N_EDGES);        float* ecoef2 = alloc(N_EDGES);
  float* h0   = alloc(D6);  float* c0 = alloc(D6);  float* cvec = alloc(4*D6);
  float* ebuf = alloc(2*N_NODES);  float* abuf = alloc(2*N_NODES);
  float* Abuf = alloc((size_t)512*D6);
  float* gates= alloc((size_t)512*4*D6);
  float* h1s  = alloc((size_t)512*D6);
  float* zbuf = alloc((size_t)256*3072);
  float* z1   = alloc((size_t)256*256);
  float* z2b  = alloc((size_t)256*128);
  float* pbuf = alloc((size_t)4*512*3072);   // split-K partials (reused by all 3 GEMMs)
  int* cnt1 = (int*)alloc(NB);   int* cnt2 = (int*)alloc(NB);
  int* st1  = (int*)alloc(NB+1); int* st2  = (int*)alloc(NB+1);
  int* ecnt1= (int*)alloc(N_NODES); int* ecnt2 = (int*)alloc(N_NODES);
  int* eoff1= (int*)alloc(N_NODES+1); int* eoff2 = (int*)alloc(N_NODES+1);
  int* ecur1= (int*)alloc(N_NODES); int* ecur2 = (int*)alloc(N_NODES);
  int* esrc1= (int*)alloc(N_EDGES); int* esrc2 = (int*)alloc(N_EDGES);
  (void)ws_size; (void)in_sizes; (void)n_in; (void)out_size;

  k_init   <<<32,256,0,stream>>>(deg1,deg2,ecnt1,ecnt2,cnt1,cnt2);
  k_deg    <<<1024,256,0,stream>>>(ei1,ea1,deg1,ecnt1, ei2,ea2,deg2,ecnt2);
  k_count  <<<32,256,0,stream>>>(batch1,batch2,cnt1,cnt2);
  k_dinv   <<<32,256,0,stream>>>(deg1,deg2);
  k_coef   <<<1024,256,0,stream>>>(ei1,ea1,deg1,coef1, ei2,ea2,deg2,coef2);
  k_scan256<<<2,256,0,stream>>>(cnt1,cnt2,st1,st2);
  k_escan  <<<2,1024,0,stream>>>(ecnt1,ecnt2,eoff1,ecur1,eoff2,ecur2);
  k_fill   <<<1024,256,0,stream>>>(ei1,coef1,ecur1,esrc1,ecoef1, ei2,coef2,ecur2,esrc2,ecoef2);

  const float* Ws[3]={W0,W1,W2}; const float* bs[3]={b0,b1,b2};
  for (int l=0;l<3;l++){
    const float* x1 = (l==0)? feat1 : (h1 + (l-1)*NH);
    const float* x2 = (l==0)? feat2 : (h2 + (l-1)*NH);
    int xs = (l==0)? 64 : D3;
    int K  = (l==0)? 64 : NH;
    k_xw    <<<2048,128,0,stream>>>(x1,x2,xs,K,Ws[l],xw1,xw2);
    k_gather<<<16384,128,0,stream>>>(xw1,xw2,eoff1,eoff2,esrc1,esrc2,ecoef1,ecoef2,
                                     deg1,deg2,bs[l],h1,h2,l*NH);
  }

  k_l2norm  <<<16384,128,0,stream>>>(h1,h2,f1,f2);
  k_interact<<<16384,384,0,stream>>>(f1,f2,batch1,batch2,st1,st2);

  k_h0  <<<1,768,0,stream>>>(bih,bhh,h0,c0);
  k_cvec<<<3072,64,0,stream>>>(Wih,Whh,bih,bhh,h0,cvec);

  // step-1 attention with shared h0
  k_e   <<<16384,256,0,stream>>>(f1,f2,h0,0,batch1,batch2,ebuf);
  k_attn<<<512,64,0,stream>>>(ebuf,st1,st2,abuf);
  k_r   <<<512,256,0,stream>>>(f1,f2,abuf,st1,st2,Abuf,(long)256*D6,D6);

  // gates = Abuf @ WihR^T + cvec  (M=512, N=3072, K=768) : split-K=4
  k_gemm_sk<<<dim3(48,8,4),256,0,stream>>>(Abuf,D6, Wih+D6,2*D6, pbuf, 512, 3072, 192);
  k_reduce <<<6144,256,0,stream>>>(pbuf,4,(long)512*3072, cvec, gates, 3072, 0);
  k_lstm1  <<<1536,256,0,stream>>>(gates,c0,h1s,zbuf);

  // step-2 attention with per-segment h
  k_e   <<<16384,256,0,stream>>>(f1,f2,h1s,1,batch1,batch2,ebuf);
  k_attn<<<512,64,0,stream>>>(ebuf,st1,st2,abuf);
  k_r   <<<512,256,0,stream>>>(f1,f2,abuf,st1,st2,zbuf+768,1536,3072);

  // MLP
  // z1 = relu(zbuf@Wp1^T+bp1): M=256,N=256,K=3072, split-K=16 (kchunk 192)
  k_gemm_sk<<<dim3(4,4,16),256,0,stream>>>(zbuf,3072, Wp1,3072, pbuf, 256, 256, 192);
  k_reduce <<<256,256,0,stream>>>(pbuf,16,(long)256*256, bp1, z1, 256, 1);
  // z2 = relu(z1@Wp2^T+bp2): M=256,N=128,K=256, split-K=4 (kchunk 64)
  k_gemm_sk<<<dim3(2,4,4),256,0,stream>>>(z1,256, Wp2,256, pbuf, 256, 128, 64);
  k_reduce <<<128,256,0,stream>>>(pbuf,4,(long)256*128, bp2, z2b, 128, 1);
  k_p3  <<<256,128,0,stream>>>(z2b,Wp3,bp3,out);
}

// Round 4
// 521.628 us; speedup vs baseline: 2.9881x; 1.0366x over previous
//
#include <hip/hip_runtime.h>
#include <cmath>

#define N_NODES 8192
#define N_EDGES 131072
#define NB      256
#define NH      128
#define D3      384
#define D6      768
#define SMAX    96   // max nodes per (graph,side); Binomial(8192,1/256) mean 32, 96 = 11 sigma

__device__ __forceinline__ float sigf(float x){ return 1.0f/(1.0f+__expf(-x)); }

// ---------- setup ----------

__global__ void k_init(float* deg1, float* deg2, int* ecnt1, int* ecnt2, int* cnt1, int* cnt2){
  int t = blockIdx.x*blockDim.x + threadIdx.x;
  if (t < N_NODES){ deg1[t]=1.f; deg2[t]=1.f; ecnt1[t]=0; ecnt2[t]=0; }
  if (t < NB){ cnt1[t]=0; cnt2[t]=0; }
}

// weighted degree + in-edge count (both sides) + batch counts piggybacked
__global__ void k_deg(const int* __restrict__ ei1, const float* __restrict__ ea1, float* deg1, int* ecnt1,
                      const int* __restrict__ ei2, const float* __restrict__ ea2, float* deg2, int* ecnt2,
                      const int* __restrict__ b1, const int* __restrict__ b2, int* cnt1, int* cnt2){
  int idx = blockIdx.x*blockDim.x + threadIdx.x;
  int side = idx >= N_EDGES;
  int e = idx & (N_EDGES-1);
  const int* ei = side? ei2:ei1; const float* ea = side? ea2:ea1;
  float* deg = side? deg2:deg1;  int* ecnt = side? ecnt2:ecnt1;
  int d = ei[N_EDGES+e];
  atomicAdd(&deg[d], ea[e]);
  atomicAdd(&ecnt[d], 1);
  if (idx < N_NODES){ atomicAdd(&cnt1[b1[idx]],1); atomicAdd(&cnt2[b2[idx]],1); }
}

__global__ void k_dinv(float* deg1, float* deg2){
  int t = blockIdx.x*blockDim.x + threadIdx.x;
  if (t < N_NODES){ deg1[t]=rsqrtf(deg1[t]); deg2[t]=rsqrtf(deg2[t]); }
}

__global__ __launch_bounds__(256) void k_scan256(const int* c1, const int* c2, int* s1, int* s2){
  const int* c = blockIdx.x? c2:c1; int* st = blockIdx.x? s2:s1;
  __shared__ int ps[256];
  int t = threadIdx.x;
  ps[t]=c[t]; __syncthreads();
  for (int d=1; d<256; d<<=1){
    int v = (t>=d)? ps[t-d]:0;
    __syncthreads();
    ps[t]+=v;
    __syncthreads();
  }
  st[t+1]=ps[t];
  if (t==0) st[0]=0;
}

__global__ __launch_bounds__(1024) void k_escan(const int* ec1, const int* ec2,
                                                int* off1, int* cur1, int* off2, int* cur2){
  const int* cnt = blockIdx.x? ec2:ec1;
  int* off = blockIdx.x? off2:off1;
  int* cur = blockIdx.x? cur2:cur1;
  __shared__ int ps[1024];
  int t = threadIdx.x;
  int base = t*8;
  int loc[8]; int s=0;
  #pragma unroll
  for (int k=0;k<8;k++){ loc[k]=s; s+=cnt[base+k]; }
  ps[t]=s; __syncthreads();
  for (int d=1; d<1024; d<<=1){
    int v = (t>=d)? ps[t-d]:0;
    __syncthreads();
    ps[t]+=v;
    __syncthreads();
  }
  int pre = (t==0)? 0 : ps[t-1];
  #pragma unroll
  for (int k=0;k<8;k++){ int v=pre+loc[k]; off[base+k]=v; cur[base+k]=v; }
  if (t==1023) off[N_NODES]=ps[1023];
}

// CSR fill with inline norm coefficient dinv[s]*w*dinv[d]
__global__ void k_fill(const int* __restrict__ ei1, const float* __restrict__ ea1, const float* __restrict__ d1,
                       int* cur1, int* es1, float* ec1,
                       const int* __restrict__ ei2, const float* __restrict__ ea2, const float* __restrict__ d2,
                       int* cur2, int* es2, float* ec2){
  int idx = blockIdx.x*blockDim.x + threadIdx.x;
  int side = idx >= N_EDGES;
  int e = idx & (N_EDGES-1);
  const int* ei = side? ei2:ei1; const float* ea = side? ea2:ea1;
  const float* dinv = side? d2:d1;
  int* cur = side? cur2:cur1; int* es = side? es2:es1; float* ec = side? ec2:ec1;
  int s = ei[e], d = ei[N_EDGES+e];
  int pos = atomicAdd(&cur[d], 1);
  es[pos] = s;
  ec[pos] = dinv[s]*ea[e]*dinv[d];
}

// ---------- GCN ----------

__global__ __launch_bounds__(128) void k_xw(const float* __restrict__ x1, const float* __restrict__ x2,
                                            int xs, int K, const float* __restrict__ W,
                                            float* __restrict__ xw1, float* __restrict__ xw2){
  __shared__ float xr[8][128];
  int blk = blockIdx.x;
  int side = blk >> 10; int b = blk & 1023;
  const float* x = side? x2:x1;
  float* xw = side? xw2:xw1;
  int i0 = b*8;
  int c = threadIdx.x;
  for (int idx=c; idx<8*K; idx+=128){
    int r = idx / K, k = idx - r*K;
    xr[r][k] = x[(size_t)(i0+r)*xs + k];
  }
  __syncthreads();
  float acc[8]={0,0,0,0,0,0,0,0};
  for (int k=0;k<K;k++){
    float w = W[k*NH+c];
    #pragma unroll
    for (int r=0;r<8;r++) acc[r]+=xr[r][k]*w;
  }
  #pragma unroll
  for (int r=0;r<8;r++) xw[(size_t)(i0+r)*NH+c]=acc[r];
}

// fused self-loop + CSR gather + bias + leaky; 8 nodes per block, float4 channels
__global__ __launch_bounds__(256) void k_gather(const float* __restrict__ xw1, const float* __restrict__ xw2,
                                                const int* __restrict__ off1, const int* __restrict__ off2,
                                                const int* __restrict__ es1, const int* __restrict__ es2,
                                                const float* __restrict__ ec1, const float* __restrict__ ec2,
                                                const float* __restrict__ d1, const float* __restrict__ d2,
                                                const float* __restrict__ b,
                                                float* __restrict__ h1, float* __restrict__ h2, int loff){
  int blk = blockIdx.x;
  int side = blk >> 10; int bb = blk & 1023;
  const float4* xw = (const float4*)(side? xw2:xw1);
  const int* off = side? off2:off1;
  const int* es  = side? es2:es1;
  const float* ec= side? ec2:ec1;
  const float* dinv = side? d2:d1;
  float* h = side? h2:h1;
  int t = threadIdx.x;
  int i = bb*8 + (t>>5);
  int c4 = t & 31;
  float dv = dinv[i];
  float4 v = xw[(size_t)i*32 + c4];
  float sc = dv*dv;
  float4 acc = {v.x*sc, v.y*sc, v.z*sc, v.w*sc};
  int r = off[i], r1 = off[i+1];
  for (; r+1<r1; r+=2){
    int s0=es[r], s1=es[r+1];
    float w0=ec[r], w1=ec[r+1];
    float4 u0 = xw[(size_t)s0*32 + c4];
    float4 u1 = xw[(size_t)s1*32 + c4];
    acc.x += u0.x*w0 + u1.x*w1; acc.y += u0.y*w0 + u1.y*w1;
    acc.z += u0.z*w0 + u1.z*w1; acc.w += u0.w*w0 + u1.w*w1;
  }
  if (r<r1){
    int s0=es[r]; float w0=ec[r];
    float4 u0 = xw[(size_t)s0*32 + c4];
    acc.x+=u0.x*w0; acc.y+=u0.y*w0; acc.z+=u0.z*w0; acc.w+=u0.w*w0;
  }
  float4 bv = ((const float4*)b)[c4];
  acc.x+=bv.x; acc.y+=bv.y; acc.z+=bv.z; acc.w+=bv.w;
  acc.x = (acc.x>0.f)?acc.x:0.2f*acc.x;
  acc.y = (acc.y>0.f)?acc.y:0.2f*acc.y;
  acc.z = (acc.z>0.f)?acc.z:0.2f*acc.z;
  acc.w = (acc.w>0.f)?acc.w:0.2f*acc.w;
  ((float4*)(h + (size_t)i*D3 + loff))[c4] = acc;
}

// ---------- l2 normalize ----------
__global__ __launch_bounds__(128) void k_l2norm(const float* __restrict__ h1, const float* __restrict__ h2,
                                                float* __restrict__ f1, float* __restrict__ f2){
  int blk = blockIdx.x;
  int side = blk >> 13; int i = blk & (N_NODES-1);
  const float* h = side? h2:h1; float* f = side? f2:f1;
  int t = threadIdx.x;
  float v0=h[(size_t)i*D3+t], v1=h[(size_t)i*D3+128+t], v2=h[(size_t)i*D3+256+t];
  float ss = v0*v0+v1*v1+v2*v2;
  #pragma unroll
  for (int o=32;o;o>>=1) ss += __shfl_down(ss,o,64);
  __shared__ float ws[2];
  if ((t&63)==0) ws[t>>6]=ss;
  __syncthreads();
  float scale = 1.0f/fmaxf(sqrtf(ws[0]+ws[1]), 1e-12f);
  f[(size_t)i*D6+t]      =v0*scale;
  f[(size_t)i*D6+128+t]  =v1*scale;
  f[(size_t)i*D6+256+t]  =v2*scale;
}

// ---------- interaction: one block per graph, S computed once in LDS ----------
// S[i][j] = dot(A_i, B_j) over 384 ch; out1[i]=S.B rows, out2[j]=S^T.A rows
__global__ __launch_bounds__(512) void k_interact(float* __restrict__ f1, float* __restrict__ f2,
                                                  const int* __restrict__ st1, const int* __restrict__ st2){
  __shared__ float S[SMAX][SMAX+1];   // 37.25 KB
  int g = blockIdx.x;
  int i0 = st1[g]; int n1 = st1[g+1]-i0; if (n1>SMAX) n1=SMAX;
  int j0 = st2[g]; int n2 = st2[g+1]-j0; if (n2>SMAX) n2=SMAX;
  const float* A = f1 + (size_t)i0*D6;
  const float* B = f2 + (size_t)j0*D6;
  int t = threadIdx.x, w = t>>6, lane = t&63;

  // phase 1: S (4 rows of A per wave-iteration; lanes = 64 x 3 float2 = 384 ch)
  for (int ib = w*4; ib < n1; ib += 32){
    float2 a[4][3];
    #pragma unroll
    for (int r=0;r<4;r++){
      if (ib+r < n1){
        const float2* ar = (const float2*)(A + (size_t)(ib+r)*D6);
        a[r][0]=ar[lane]; a[r][1]=ar[64+lane]; a[r][2]=ar[128+lane];
      } else {
        a[r][0]=a[r][1]=a[r][2]=make_float2(0.f,0.f);
      }
    }
    for (int j=0;j<n2;j++){
      const float2* br = (const float2*)(B + (size_t)j*D6);
      float2 b0=br[lane], b1=br[64+lane], b2=br[128+lane];
      float p[4];
      #pragma unroll
      for (int r=0;r<4;r++)
        p[r] = a[r][0].x*b0.x + a[r][0].y*b0.y + a[r][1].x*b1.x
             + a[r][1].y*b1.y + a[r][2].x*b2.x + a[r][2].y*b2.y;
      #pragma unroll
      for (int r=0;r<4;r++)
        #pragma unroll
        for (int m=1;m<64;m<<=1) p[r] += __shfl_xor(p[r],m,64);
      if (lane==0){
        #pragma unroll
        for (int r=0;r<4;r++) if (ib+r<n1) S[ib+r][j]=p[r];
      }
    }
  }
  __syncthreads();

  // phase 2a: out1[i] = sum_j S[i][j]*B_j
  for (int ib = w*4; ib < n1; ib += 32){
    float2 acc[4][3];
    #pragma unroll
    for (int r=0;r<4;r++) acc[r][0]=acc[r][1]=acc[r][2]=make_float2(0.f,0.f);
    for (int j=0;j<n2;j++){
      const float2* br = (const float2*)(B + (size_t)j*D6);
      float2 b0=br[lane], b1=br[64+lane], b2=br[128+lane];
      float s[4];
      #pragma unroll
      for (int r=0;r<4;r++) s[r]=S[ib+r][j];
      #pragma unroll
      for (int r=0;r<4;r++){
        acc[r][0].x+=s[r]*b0.x; acc[r][0].y+=s[r]*b0.y;
        acc[r][1].x+=s[r]*b1.x; acc[r][1].y+=s[r]*b1.y;
        acc[r][2].x+=s[r]*b2.x; acc[r][2].y+=s[r]*b2.y;
      }
    }
    #pragma unroll
    for (int r=0;r<4;r++) if (ib+r<n1){
      float2* o = (float2*)(f1 + (size_t)(i0+ib+r)*D6 + D3);
      o[lane]=acc[r][0]; o[64+lane]=acc[r][1]; o[128+lane]=acc[r][2];
    }
  }

  // phase 2b: out2[j] = sum_i S[i][j]*A_i
  for (int jb = w*4; jb < n2; jb += 32){
    float2 acc[4][3];
    #pragma unroll
    for (int r=0;r<4;r++) acc[r][0]=acc[r][1]=acc[r][2]=make_float2(0.f,0.f);
    for (int i=0;i<n1;i++){
      const float2* ar = (const float2*)(A + (size_t)i*D6);
      float2 a0=ar[lane], a1=ar[64+lane], a2=ar[128+lane];
      float s[4];
      #pragma unroll
      for (int r=0;r<4;r++) s[r]=S[i][jb+r];
      #pragma unroll
      for (int r=0;r<4;r++){
        acc[r][0].x+=s[r]*a0.x; acc[r][0].y+=s[r]*a0.y;
        acc[r][1].x+=s[r]*a1.x; acc[r][1].y+=s[r]*a1.y;
        acc[r][2].x+=s[r]*a2.x; acc[r][2].y+=s[r]*a2.y;
      }
    }
    #pragma unroll
    for (int r=0;r<4;r++) if (jb+r<n2){
      float2* o = (float2*)(f2 + (size_t)(j0+jb+r)*D6 + D3);
      o[lane]=acc[r][0]; o[64+lane]=acc[r][1]; o[128+lane]=acc[r][2];
    }
  }
}

// ---------- set2set ----------

__global__ void k_h0(const float* bih, const float* bhh, float* h0, float* c0){
  int j = threadIdx.x;
  float gi = bih[j]      + bhh[j];
  float gg = bih[2*D6+j] + bhh[2*D6+j];
  float go = bih[3*D6+j] + bhh[3*D6+j];
  float c = sigf(gi)*tanhf(gg);
  c0[j]=c;
  h0[j]=sigf(go)*tanhf(c);
}

// cvec[j] = h0 . (Wih[j,0:768]+Whh[j,:]) + bih[j]+bhh[j]; float4 loads
__global__ __launch_bounds__(64) void k_cvec(const float* __restrict__ Wih, const float* __restrict__ Whh,
                                             const float* bih, const float* bhh,
                                             const float* __restrict__ h0, float* __restrict__ cvec){
  int j = blockIdx.x, lane = threadIdx.x;
  const float4* wi = (const float4*)(Wih + (size_t)j*(2*D6));
  const float4* wh = (const float4*)(Whh + (size_t)j*D6);
  const float4* h4 = (const float4*)h0;
  float acc=0;
  #pragma unroll
  for (int m=0;m<3;m++){
    float4 hv = h4[m*64+lane];
    float4 a = wi[m*64+lane];
    float4 b = wh[m*64+lane];
    acc += hv.x*(a.x+b.x) + hv.y*(a.y+b.y) + hv.z*(a.z+b.z) + hv.w*(a.w+b.w);
  }
  #pragma unroll
  for (int m=1;m<64;m<<=1) acc += __shfl_xor(acc,m,64);
  if (lane==0) cvec[j]=acc+bih[j]+bhh[j];
}

// fused attention step: e = x.hv per node, segment softmax, r = sum a*x
// one block per (side, segment); 256 threads (4 waves)
__global__ __launch_bounds__(256) void k_att(const float* __restrict__ f1, const float* __restrict__ f2,
                                             const float* __restrict__ hbase, int perseg,
                                             const int* __restrict__ st1, const int* __restrict__ st2,
                                             float* __restrict__ dst0, long sidestep, long dstride){
  __shared__ float4 hs[192];
  __shared__ float e_s[SMAX];
  int side = blockIdx.x >> 8, g = blockIdx.x & (NB-1);
  const int* st = side? st2:st1;
  int n0 = st[g]; int cnt = st[g+1]-n0; if (cnt>SMAX) cnt=SMAX;
  const float* x = (side? f2:f1) + (size_t)n0*D6;
  const float* hv = hbase + (perseg? (size_t)(side*NB+g)*D6 : 0);
  int t = threadIdx.x, w = t>>6, lane = t&63;
  if (t<192) hs[t] = ((const float4*)hv)[t];
  __syncthreads();
  // e[n]
  for (int n=w; n<cnt; n+=4){
    const float4* xr = (const float4*)(x + (size_t)n*D6);
    float p = 0;
    #pragma unroll
    for (int m=0;m<3;m++){
      float4 xv = xr[m*64+lane];
      float4 hvv = hs[m*64+lane];
      p += xv.x*hvv.x + xv.y*hvv.y + xv.z*hvv.z + xv.w*hvv.w;
    }
    #pragma unroll
    for (int m=1;m<64;m<<=1) p += __shfl_xor(p,m,64);
    if (lane==0) e_s[n]=p;
  }
  __syncthreads();
  // softmax over e_s[0:cnt] by wave 0 (in place)
  if (w==0){
    float mx=-INFINITY;
    for (int n=lane;n<cnt;n+=64) mx=fmaxf(mx,e_s[n]);
    #pragma unroll
    for (int m=1;m<64;m<<=1) mx=fmaxf(mx,__shfl_xor(mx,m,64));
    float s=0;
    for (int n=lane;n<cnt;n+=64) s+=__expf(e_s[n]-mx);
    #pragma unroll
    for (int m=1;m<64;m<<=1) s+=__shfl_xor(s,m,64);
    float inv=1.0f/s;
    for (int n=lane;n<cnt;n+=64) e_s[n]=__expf(e_s[n]-mx)*inv;
  }
  __syncthreads();
  // r = sum a*x  (192 threads x float4 = 768 ch)
  if (t<192){
    float4 acc={0,0,0,0};
    for (int n=0;n<cnt;n++){
      float a = e_s[n];
      float4 xv = ((const float4*)(x + (size_t)n*D6))[t];
      acc.x+=a*xv.x; acc.y+=a*xv.y; acc.z+=a*xv.z; acc.w+=a*xv.w;
    }
    ((float4*)(dst0 + side*sidestep + (size_t)g*dstride))[t]=acc;
  }
}

// split-K GEMM: partial[s][M x N] = A[M x K-chunk] @ B^T-chunk
__global__ __launch_bounds__(256) void k_gemm_sk(const float* __restrict__ A, int lda,
                                                 const float* __restrict__ B, int ldb,
                                                 float* __restrict__ partial,
                                                 int M, int N, int kchunk){
  __shared__ float As[16][68];
  __shared__ float Bs[16][68];
  int bm = blockIdx.y*64, bn = blockIdx.x*64;
  int kbase = blockIdx.z*kchunk;
  int t = threadIdx.x;
  int tx = t & 15, ty = t >> 4;
  float acc[4][4] = {};
  for (int k0=kbase;k0<kbase+kchunk;k0+=16){
    for (int l=t;l<64*16;l+=256){
      int m = l>>4, k = l&15;
      As[k][m] = A[(size_t)(bm+m)*lda + k0+k];
      Bs[k][m] = B[(size_t)(bn+m)*ldb + k0+k];
    }
    __syncthreads();
    #pragma unroll
    for (int k=0;k<16;k++){
      float4 av = *(const float4*)&As[k][ty*4];
      float4 bv = *(const float4*)&Bs[k][tx*4];
      float a4[4]={av.x,av.y,av.z,av.w};
      float b4[4]={bv.x,bv.y,bv.z,bv.w};
      #pragma unroll
      for (int i=0;i<4;i++)
        #pragma unroll
        for (int j=0;j<4;j++) acc[i][j]+=a4[i]*b4[j];
    }
    __syncthreads();
  }
  float* pout = partial + (size_t)blockIdx.z*M*N;
  #pragma unroll
  for (int i=0;i<4;i++)
    #pragma unroll
    for (int j=0;j<4;j++){
      int m = bm+ty*4+i, n = bn+tx*4+j;
      pout[(size_t)m*N+n]=acc[i][j];
    }
}

__global__ __launch_bounds__(256) void k_reduce(const float* __restrict__ partial, int S, long MN,
                                                const float* __restrict__ cv, float* __restrict__ dst,
                                                int N, int act){
  long idx = (long)blockIdx.x*256 + threadIdx.x;
  if (idx >= MN) return;
  float s = 0;
  for (int p=0;p<S;p++) s += partial[(size_t)p*MN + idx];
  s += cv[idx % N];
  if (act) s = fmaxf(s,0.f);
  dst[idx]=s;
}

__global__ void k_lstm1(const float* __restrict__ gates, const float* __restrict__ c0,
                        float* __restrict__ h1s, float* __restrict__ z){
  int t = blockIdx.x*blockDim.x + threadIdx.x;
  int m = t/D6, j = t - m*D6;
  const float* gr = gates + (size_t)m*4*D6;
  float gi=gr[j], gf=gr[D6+j], gg=gr[2*D6+j], go=gr[3*D6+j];
  float c = sigf(gf)*c0[j] + sigf(gi)*tanhf(gg);
  float h = sigf(go)*tanhf(c);
  h1s[t]=h;
  int side = m>>8, g = m&255;
  z[(size_t)g*3072 + side*1536 + j]=h;
}

__global__ __launch_bounds__(128) void k_p3(const float* __restrict__ z2, const float* __restrict__ W,
                                            const float* b, float* __restrict__ out){
  int m=blockIdx.x, t=threadIdx.x;
  float p = z2[m*128+t]*W[t];
  #pragma unroll
  for (int o=32;o;o>>=1) p += __shfl_down(p,o,64);
  __shared__ float ws[2];
  if ((t&63)==0) ws[t>>6]=p;
  __syncthreads();
  if (t==0){ float v=ws[0]+ws[1]+b[0]; out[m]=1.0f/(1.0f+__expf(-v)); }
}

// ---------- launch ----------

extern "C" void kernel_launch(void* const* d_in, const int* in_sizes, int n_in,
                              void* d_out, int out_size, void* d_ws, size_t ws_size,
                              hipStream_t stream){
  const float* feat1=(const float*)d_in[0];
  const float* feat2=(const float*)d_in[1];
  const float* ea1  =(const float*)d_in[2];
  const float* ea2  =(const float*)d_in[3];
  const float* W0=(const float*)d_in[4];  const float* b0=(const float*)d_in[5];
  const float* W1=(const float*)d_in[6];  const float* b1=(const float*)d_in[7];
  const float* W2=(const float*)d_in[8];  const float* b2=(const float*)d_in[9];
  const float* Wih=(const float*)d_in[10]; const float* bih=(const float*)d_in[11];
  const float* Whh=(const float*)d_in[12]; const float* bhh=(const float*)d_in[13];
  const float* Wp1=(const float*)d_in[14]; const float* bp1=(const float*)d_in[15];
  const float* Wp2=(const float*)d_in[16]; const float* bp2=(const float*)d_in[17];
  const float* Wp3=(const float*)d_in[18]; const float* bp3=(const float*)d_in[19];
  const int* ei1=(const int*)d_in[20]; const int* ei2=(const int*)d_in[21];
  const int* batch1=(const int*)d_in[22]; const int* batch2=(const int*)d_in[23];
  float* out = (float*)d_out;

  float* base = (float*)d_ws;
  size_t off = 0;
  auto alloc = [&](size_t n)->float* { float* r = base + off; off += (n + 255) & ~(size_t)255; return r; };
  float* deg1 = alloc(N_NODES);          float* deg2 = alloc(N_NODES);
  float* xw1  = alloc((size_t)N_NODES*NH); float* xw2 = alloc((size_t)N_NODES*NH);
  float* h1   = alloc((size_t)N_NODES*D3);
  float* h2   = alloc((size_t)N_NODES*D3);
  float* f1   = alloc((size_t)N_NODES*D6);
  float* f2   = alloc((size_t)N_NODES*D6);
  float* ecoef1 = alloc(N_EDGES);        float* ecoef2 = alloc(N_EDGES);
  float* h0   = alloc(D6);  float* c0 = alloc(D6);  float* cvec = alloc(4*D6);
  float* Abuf = alloc((size_t)512*D6);
  float* gates= alloc((size_t)512*4*D6);
  float* h1s  = alloc((size_t)512*D6);
  float* zbuf = alloc((size_t)256*3072);
  float* z1   = alloc((size_t)256*256);
  float* z2b  = alloc((size_t)256*128);
  float* pbuf = alloc((size_t)4*512*3072);
  int* cnt1 = (int*)alloc(NB);   int* cnt2 = (int*)alloc(NB);
  int* st1  = (int*)alloc(NB+1); int* st2  = (int*)alloc(NB+1);
  int* ecnt1= (int*)alloc(N_NODES); int* ecnt2 = (int*)alloc(N_NODES);
  int* eoff1= (int*)alloc(N_NODES+1); int* eoff2 = (int*)alloc(N_NODES+1);
  int* ecur1= (int*)alloc(N_NODES); int* ecur2 = (int*)alloc(N_NODES);
  int* esrc1= (int*)alloc(N_EDGES); int* esrc2 = (int*)alloc(N_EDGES);
  (void)ws_size; (void)in_sizes; (void)n_in; (void)out_size;

  k_init   <<<32,256,0,stream>>>(deg1,deg2,ecnt1,ecnt2,cnt1,cnt2);
  k_deg    <<<1024,256,0,stream>>>(ei1,ea1,deg1,ecnt1, ei2,ea2,deg2,ecnt2, batch1,batch2,cnt1,cnt2);
  k_dinv   <<<32,256,0,stream>>>(deg1,deg2);
  k_scan256<<<2,256,0,stream>>>(cnt1,cnt2,st1,st2);
  k_escan  <<<2,1024,0,stream>>>(ecnt1,ecnt2,eoff1,ecur1,eoff2,ecur2);
  k_fill   <<<1024,256,0,stream>>>(ei1,ea1,deg1,ecur1,esrc1,ecoef1, ei2,ea2,deg2,ecur2,esrc2,ecoef2);

  const float* Ws[3]={W0,W1,W2}; const float* bs[3]={b0,b1,b2};
  for (int l=0;l<3;l++){
    const float* x1 = (l==0)? feat1 : (h1 + (l-1)*NH);
    const float* x2 = (l==0)? feat2 : (h2 + (l-1)*NH);
    int xs = (l==0)? 64 : D3;
    int K  = (l==0)? 64 : NH;
    k_xw    <<<2048,128,0,stream>>>(x1,x2,xs,K,Ws[l],xw1,xw2);
    k_gather<<<2048,256,0,stream>>>(xw1,xw2,eoff1,eoff2,esrc1,esrc2,ecoef1,ecoef2,
                                    deg1,deg2,bs[l],h1,h2,l*NH);
  }

  k_l2norm  <<<16384,128,0,stream>>>(h1,h2,f1,f2);
  k_interact<<<256,512,0,stream>>>(f1,f2,st1,st2);

  k_h0  <<<1,768,0,stream>>>(bih,bhh,h0,c0);
  k_cvec<<<3072,64,0,stream>>>(Wih,Whh,bih,bhh,h0,cvec);

  // step-1 attention (shared h0) -> Abuf rows [side*256+g]
  k_att<<<512,256,0,stream>>>(f1,f2,h0,0,st1,st2,Abuf,(long)256*D6,(long)D6);

  // gates = Abuf @ WihR^T + cvec  (M=512,N=3072,K=768), split-K=4
  k_gemm_sk<<<dim3(48,8,4),256,0,stream>>>(Abuf,D6, Wih+D6,2*D6, pbuf, 512, 3072, 192);
  k_reduce <<<6144,256,0,stream>>>(pbuf,4,(long)512*3072, cvec, gates, 3072, 0);
  k_lstm1  <<<1536,256,0,stream>>>(gates,c0,h1s,zbuf);

  // step-2 attention (per-segment h) -> zbuf r-slots
  k_att<<<512,256,0,stream>>>(f1,f2,h1s,1,st1,st2,zbuf+768,(long)1536,(long)3072);

  // MLP
  k_gemm_sk<<<dim3(4,4,16),256,0,stream>>>(zbuf,3072, Wp1,3072, pbuf, 256, 256, 192);
  k_reduce <<<256,256,0,stream>>>(pbuf,16,(long)256*256, bp1, z1, 256, 1);
  k_gemm_sk<<<dim3(2,4,4),256,0,stream>>>(z1,256, Wp2,256, pbuf, 256, 128, 64);
  k_reduce <<<128,256,0,stream>>>(pbuf,4,(long)256*128, bp2, z2b, 128, 1);
  k_p3  <<<256,128,0,stream>>>(z2b,Wp3,bp3,out);
}